// Round 1
// 439.779 us; speedup vs baseline: 1.0030x; 1.0030x over previous
//
#include <hip/hip_runtime.h>
#include <hip/hip_bf16.h>
#include <stdint.h>

typedef __attribute__((ext_vector_type(8))) short bf16x8;
typedef __attribute__((ext_vector_type(4))) float f32x4;
typedef __attribute__((ext_vector_type(4))) _Float16 f16x4;
typedef __attribute__((ext_vector_type(8))) _Float16 f16x8;
typedef __attribute__((ext_vector_type(4))) unsigned short u16x4;

__device__ __forceinline__ float b2f(unsigned short u){
  union { unsigned int i; float f; } x; x.i = ((unsigned int)u) << 16; return x.f;
}
__device__ __forceinline__ unsigned short f2b(float f){
  union { float f; unsigned int i; } x; x.f = f;
  unsigned int r = x.i + 0x7fffu + ((x.i >> 16) & 1u);
  return (unsigned short)(r >> 16);
}

__device__ __forceinline__ void gld_lds16(const void* g, void* l){
  __builtin_amdgcn_global_load_lds((const __attribute__((address_space(1))) unsigned int*)g,
                                   (__attribute__((address_space(3))) unsigned int*)l,
                                   16, 0, 0);
}

// ---------------- transpose + fp32->bf16: in (R x C) fp32 -> out (C x R) bf16 ----------------
__global__ __launch_bounds__(256) void transpose_k(const float* __restrict__ in,
                                                   unsigned short* __restrict__ out,
                                                   int R, int C){
  __shared__ unsigned short tile[32][33];
  int tx = threadIdx.x & 31, ty = threadIdx.x >> 5;
  int r0 = blockIdx.y * 32, c0 = blockIdx.x * 32;
#pragma unroll
  for (int t = 0; t < 4; ++t)
    tile[ty + t*8][tx] = f2b(in[(size_t)(r0 + ty + t*8) * C + c0 + tx]);
  __syncthreads();
#pragma unroll
  for (int t = 0; t < 4; ++t)
    out[(size_t)(c0 + ty + t*8) * R + r0 + tx] = tile[tx][ty + t*8];
}

// ---------------- ss init: ss[which][b][j] = bias_which[j] ----------------
__global__ __launch_bounds__(256) void ss_init_k(const float* __restrict__ bssq,
                                                 const float* __restrict__ bssk,
                                                 float* __restrict__ ss_q,
                                                 float* __restrict__ ss_kv){
  int idx = blockIdx.x*256 + threadIdx.x;          // 0..32767
  int which = idx >> 14, rem = idx & 16383;
  int j = rem & 2047;
  if (which) ss_kv[rem] = bssk[j];
  else       ss_q[rem]  = bssq[j];
}

// ---------------- ss main: ss[which][b][col] += sum_k silu(c[b][k]) * W[k][col] ----------------
__global__ __launch_bounds__(256) void ss2_k(const float* __restrict__ tvec,
                                             const float* __restrict__ Wssq,
                                             const float* __restrict__ Wssk,
                                             float* __restrict__ ss_q,
                                             float* __restrict__ ss_kv){
  const int which = blockIdx.z;
  const float* W = which ? Wssk : Wssq;
  float* ss = which ? ss_kv : ss_q;
  const int col = blockIdx.x*256 + threadIdx.x;
  const int k0 = blockIdx.y*64;

  __shared__ float sl[8][64];
  int idx = threadIdx.x;
#pragma unroll
  for (int t = 0; t < 2; ++t){
    int i = idx + t*256;
    int b = i >> 6, k = i & 63;
    float c = tvec[b*1024 + k0 + k];
    sl[b][k] = c / (1.f + __expf(-c));
  }
  __syncthreads();

  float acc[8] = {0.f,0.f,0.f,0.f,0.f,0.f,0.f,0.f};
#pragma unroll 8
  for (int k = 0; k < 64; ++k){
    float w = W[(size_t)(k0 + k)*2048 + col];
#pragma unroll
    for (int b = 0; b < 8; ++b) acc[b] += sl[b][k] * w;
  }
#pragma unroll
  for (int b = 0; b < 8; ++b)
    atomicAdd(&ss[b*2048 + col], acc[b]);
}

// ---------------- adaptive layernorm (fp32 in, bf16 out): per row of H=1024 ----------------
__global__ __launch_bounds__(256) void ada_ln_k(const float* __restrict__ x,
                                                const float* __restrict__ ss,
                                                unsigned short* __restrict__ out,
                                                int L){
  int row = blockIdx.x;
  int b = row / L;
  const float* xr = x + (size_t)row * 1024;
  int tid = threadIdx.x;
  float4 v = *(const float4*)&xr[tid*4];
  float s = v.x + v.y + v.z + v.w;
  __shared__ float red[4];
#pragma unroll
  for (int o = 32; o > 0; o >>= 1) s += __shfl_xor(s, o, 64);
  if ((tid & 63) == 0) red[tid >> 6] = s;
  __syncthreads();
  float mu = (red[0]+red[1]+red[2]+red[3]) * (1.f/1024.f);
  __syncthreads();
  float vs = (v.x-mu)*(v.x-mu) + (v.y-mu)*(v.y-mu) + (v.z-mu)*(v.z-mu) + (v.w-mu)*(v.w-mu);
#pragma unroll
  for (int o = 32; o > 0; o >>= 1) vs += __shfl_xor(vs, o, 64);
  if ((tid & 63) == 0) red[tid >> 6] = vs;
  __syncthreads();
  float var = (red[0]+red[1]+red[2]+red[3]) * (1.f/1024.f);
  float inv = rsqrtf(var + 1e-5f);
  const float* sb = ss + (size_t)b*2048;
  float4 sc = *(const float4*)&sb[tid*4];
  float4 bi = *(const float4*)&sb[1024 + tid*4];
  u16x4 o4;
  o4[0] = f2b((1.f + sc.x) * ((v.x-mu)*inv) + bi.x);
  o4[1] = f2b((1.f + sc.y) * ((v.y-mu)*inv) + bi.y);
  o4[2] = f2b((1.f + sc.z) * ((v.z-mu)*inv) + bi.z);
  o4[3] = f2b((1.f + sc.w) * ((v.w-mu)*inv) + bi.w);
  *(u16x4*)&out[(size_t)row*1024 + tid*4] = o4;
}

// ---------------- GEMM: C(MxN) = A(MxK,bf16) @ BT(NxK,bf16)^T + bias(fp32) ----------------
// BK=64: 32 MFMAs per barrier pair.
// XCD-aware block swizzle (T1): each XCD owns a contiguous chunk of tiles so the
// 8 N-blocks sharing an A-row-tile share one L2 instead of 8 non-coherent ones.
// mode 0: bf16 out to Cb (stride 1024)
// mode 1: fp32 out to Cf (stride N) + fp32 residual resf
// mode 2: kv split: col<1024 -> bf16 Cb (stride 1024); col>=1024 -> f16 vT[b][d][l]
__global__ __launch_bounds__(256) void gemm_bt_k(const unsigned short* __restrict__ A,
                                                 const unsigned short* __restrict__ BT,
                                                 const float* __restrict__ bias,
                                                 const float* __restrict__ resf,
                                                 unsigned short* __restrict__ Cb,
                                                 float* __restrict__ Cf,
                                                 _Float16* __restrict__ vT,
                                                 int M, int N, int K, int mode){
  __shared__ __attribute__((aligned(16))) unsigned short As[128*64];
  __shared__ __attribute__((aligned(16))) unsigned short Bs[128*64];
  const int tid = threadIdx.x;
  const int wave = tid >> 6, lane = tid & 63;
  const int lm = lane & 15, quad = lane >> 4;

  // ---- XCD swizzle: lid -> tile so that XCD k gets tiles [k*chunk, (k+1)*chunk) ----
  const int gx = gridDim.x;
  const int nwg = gx * gridDim.y;            // 1024 (Q/P) or 512 (KV): both %8==0
  const int lid = blockIdx.y * gx + blockIdx.x;
  const int chunk = nwg >> 3;
  const int tile = (lid & 7) * chunk + (lid >> 3);
  const int m0 = (tile / gx) * 128, n0 = (tile % gx) * 128;

  const int wm = (wave >> 1) * 64, wn = (wave & 1) * 64;
  f32x4 acc[4][4];
#pragma unroll
  for (int i = 0; i < 4; ++i)
#pragma unroll
    for (int j = 0; j < 4; ++j) acc[i][j] = (f32x4){0.f,0.f,0.f,0.f};

  // staging map: c = r*256+tid in [0,1024): row = c>>3, colseg = (c&7)*8
  int rowc[4], colc[4];
#pragma unroll
  for (int r = 0; r < 4; ++r){
    int c = r*256 + tid;
    rowc[r] = c >> 3; colc[r] = (c & 7) * 8;
  }

  for (int k0 = 0; k0 < K; k0 += 64){
    __syncthreads();
#pragma unroll
    for (int r = 0; r < 4; ++r)
      gld_lds16(&A[(size_t)(m0 + rowc[r])*K + k0 + colc[r]], &As[(r*256 + tid)*8]);
#pragma unroll
    for (int r = 0; r < 4; ++r)
      gld_lds16(&BT[(size_t)(n0 + rowc[r])*K + k0 + colc[r]], &Bs[(r*256 + tid)*8]);
    __syncthreads();
#pragma unroll
    for (int ks = 0; ks < 2; ++ks){
      bf16x8 af[4], bfr[4];
#pragma unroll
      for (int i = 0; i < 4; ++i)
        af[i] = *(bf16x8*)&As[(wm + i*16 + lm)*64 + ks*32 + quad*8];
#pragma unroll
      for (int j = 0; j < 4; ++j)
        bfr[j] = *(bf16x8*)&Bs[(wn + j*16 + lm)*64 + ks*32 + quad*8];
#pragma unroll
      for (int i = 0; i < 4; ++i)
#pragma unroll
        for (int j = 0; j < 4; ++j)
          acc[i][j] = __builtin_amdgcn_mfma_f32_16x16x32_bf16(af[i], bfr[j], acc[i][j], 0, 0, 0);
    }
  }

  if (mode == 2 && n0 >= 1024){
#pragma unroll
    for (int j = 0; j < 4; ++j){
      int col = n0 + wn + j*16 + lm;
      int d = col - 1024;
      float bv = bias[col];
#pragma unroll
      for (int i = 0; i < 4; ++i){
        int rowb = m0 + wm + i*16 + quad*4;
        int brow = rowb >> 9, l = rowb & 511;
        f16x4 h4;
#pragma unroll
        for (int p = 0; p < 4; ++p) h4[p] = (_Float16)(acc[i][j][p] + bv);
        *(f16x4*)&vT[((size_t)brow*1024 + d)*512 + l] = h4;
      }
    }
    return;
  }

#pragma unroll
  for (int j = 0; j < 4; ++j){
    int col = n0 + wn + j*16 + lm;
    float bv = bias[col];
#pragma unroll
    for (int i = 0; i < 4; ++i){
#pragma unroll
      for (int p = 0; p < 4; ++p){
        int row = m0 + wm + i*16 + quad*4 + p;
        float v = acc[i][j][p] + bv;
        if (mode == 1){
          Cf[(size_t)row*N + col] = v + resf[(size_t)row*N + col];
        } else {
          Cb[(size_t)row*1024 + col] = f2b(v);
        }
      }
    }
  }
}

// ---------------- attention v5: S^T + online softmax + LDS-staged K/V tiles ----------------
// XCD swizzle: each XCD owns 16 consecutive (b,h) head-slices (2 MB K/V resident per L2)
__global__ __launch_bounds__(256) void attn_k(const unsigned short* __restrict__ q,
                                              const unsigned short* __restrict__ kbuf,
                                              const _Float16* __restrict__ vT,
                                              unsigned short* __restrict__ out){
  const int lid = (blockIdx.z * gridDim.y + blockIdx.y) * gridDim.x + blockIdx.x; // 0..2047
  const int tile = (lid & 7) * 256 + (lid >> 3);
  const int qb = tile & 15, h = (tile >> 4) & 15, b = tile >> 8;
  const int tid = threadIdx.x;
  const int wave = tid >> 6, lane = tid & 63;
  const int lm = lane & 15, quad = lane >> 4;
  const int q0 = qb * 128;

  __shared__ __attribute__((aligned(16))) unsigned short Ks[64*72];
  __shared__ __attribute__((aligned(16))) _Float16      Vs[64*72];

  bf16x8 qf[2][2];
#pragma unroll
  for (int u = 0; u < 2; ++u){
    const unsigned short* qrow = q + ((size_t)b*2048 + q0 + wave*32 + u*16 + lm)*1024 + h*64;
    qf[u][0] = *(const bf16x8*)&qrow[quad*8];
    qf[u][1] = *(const bf16x8*)&qrow[32 + quad*8];
  }

  const unsigned short* kb = kbuf + ((size_t)b*512)*1024 + h*64;
  const _Float16*       vb = vT + ((size_t)b*1024 + h*64)*512;

  f32x4 oacc[2][4];
#pragma unroll
  for (int u = 0; u < 2; ++u)
#pragma unroll
    for (int nt = 0; nt < 4; ++nt) oacc[u][nt] = (f32x4){0.f,0.f,0.f,0.f};
  float m_run[2] = {-1e30f, -1e30f}, l_run[2] = {0.f, 0.f};

  const int srow = tid >> 3, scol = (tid & 7) * 8;

  for (int kt = 0; kt < 8; ++kt){
    const int l0 = kt * 64;
    __syncthreads();
#pragma unroll
    for (int r = 0; r < 2; ++r){
      int row = r*32 + srow;
      *(bf16x8*)&Ks[row*72 + scol] = *(const bf16x8*)&kb[(size_t)(l0 + row)*1024 + scol];
      *(f16x8*)&Vs[row*72 + scol]  = *(const f16x8*)&vb[(size_t)row*512 + l0 + scol];
    }
    __syncthreads();

    f32x4 sacc[2][4];
#pragma unroll
    for (int u = 0; u < 2; ++u)
#pragma unroll
      for (int s = 0; s < 4; ++s) sacc[u][s] = (f32x4){0.f,0.f,0.f,0.f};
#pragma unroll
    for (int s = 0; s < 4; ++s){
      bf16x8 kf0 = *(bf16x8*)&Ks[(s*16 + lm)*72 + quad*8];
      bf16x8 kf1 = *(bf16x8*)&Ks[(s*16 + lm)*72 + 32 + quad*8];
#pragma unroll
      for (int u = 0; u < 2; ++u){
        sacc[u][s] = __builtin_amdgcn_mfma_f32_16x16x32_bf16(kf0, qf[u][0], sacc[u][s], 0, 0, 0);
        sacc[u][s] = __builtin_amdgcn_mfma_f32_16x16x32_bf16(kf1, qf[u][1], sacc[u][s], 0, 0, 0);
      }
    }

    f16x4 pf[2][4];
#pragma unroll
    for (int u = 0; u < 2; ++u){
      float tm = -1e30f;
#pragma unroll
      for (int s = 0; s < 4; ++s)
#pragma unroll
        for (int p = 0; p < 4; ++p) tm = fmaxf(tm, sacc[u][s][p]);
      tm = fmaxf(tm, __shfl_xor(tm, 16, 64));
      tm = fmaxf(tm, __shfl_xor(tm, 32, 64));
      float m_new = fmaxf(m_run[u], tm * 0.125f);
      float alpha = __expf(m_run[u] - m_new);
      m_run[u] = m_new;
      l_run[u] *= alpha;
      float ap[4];
#pragma unroll
      for (int p = 0; p < 4; ++p) ap[p] = __shfl(alpha, quad*4 + p, 64);
#pragma unroll
      for (int nt = 0; nt < 4; ++nt){
        oacc[u][nt][0] *= ap[0]; oacc[u][nt][1] *= ap[1];
        oacc[u][nt][2] *= ap[2]; oacc[u][nt][3] *= ap[3];
      }
#pragma unroll
      for (int s = 0; s < 4; ++s)
#pragma unroll
        for (int p = 0; p < 4; ++p){
          float e = __expf(sacc[u][s][p] * 0.125f - m_new);
          l_run[u] += e;
          pf[u][s][p] = (_Float16)e;
        }
    }

#pragma unroll
    for (int s = 0; s < 4; ++s){
#pragma unroll
      for (int nt = 0; nt < 4; ++nt){
        f16x4 vf = *(const f16x4*)&Vs[(size_t)(nt*16 + lm)*72 + s*16 + quad*4];
#pragma unroll
        for (int u = 0; u < 2; ++u)
          oacc[u][nt] = __builtin_amdgcn_mfma_f32_16x16x16f16(pf[u][s], vf, oacc[u][nt], 0, 0, 0);
      }
    }
  }

#pragma unroll
  for (int u = 0; u < 2; ++u){
    float lr = l_run[u];
    lr += __shfl_xor(lr, 16, 64);
    lr += __shfl_xor(lr, 32, 64);
    float rinv = 1.f / lr;
    float rp[4];
#pragma unroll
    for (int p = 0; p < 4; ++p) rp[p] = __shfl(rinv, quad*4 + p, 64);
    const size_t obase = ((size_t)b*2048 + q0 + wave*32 + u*16) * 1024 + h*64;
#pragma unroll
    for (int nt = 0; nt < 4; ++nt)
#pragma unroll
      for (int p = 0; p < 4; ++p){
        int row = quad*4 + p;
        out[obase + (size_t)row*1024 + nt*16 + lm] = f2b(oacc[u][nt][p] * rp[p]);
      }
  }
}

extern "C" void kernel_launch(void* const* d_in, const int* in_sizes, int n_in,
                              void* d_out, int out_size, void* d_ws, size_t ws_size,
                              hipStream_t stream){
  const float* x_q  = (const float*)d_in[0];
  const float* x_kv = (const float*)d_in[1];
  const float* tvec = (const float*)d_in[2];
  const float* Wq   = (const float*)d_in[3];
  const float* bq   = (const float*)d_in[4];
  const float* Wkv  = (const float*)d_in[5];
  const float* bkv  = (const float*)d_in[6];
  const float* Wp   = (const float*)d_in[7];
  const float* bp   = (const float*)d_in[8];
  const float* Wssq = (const float*)d_in[9];
  const float* bssq = (const float*)d_in[10];
  const float* Wssk = (const float*)d_in[11];
  const float* bssk = (const float*)d_in[12];

  char* ws = (char*)d_ws;
  float*          ss_q  = (float*)(ws + 0);                    // 64 KB
  float*          ss_kv = (float*)(ws + 65536);                // 64 KB
  unsigned short* xq    = (unsigned short*)(ws + 131072);      // 32 MB bf16; reused as attn out
  unsigned short* xkv   = (unsigned short*)(ws + 33685504);    // 8 MB bf16
  unsigned short* qbuf  = (unsigned short*)(ws + 42074112);    // 32 MB bf16
  unsigned short* kbuf  = (unsigned short*)(ws + 75628544);    // 8 MB bf16
  _Float16*       vTbuf = (_Float16*)     (ws + 84017152);     // 8 MB f16
  unsigned short* WqT   = (unsigned short*)(ws + 92405760);    // 2 MB bf16
  unsigned short* WkvT  = (unsigned short*)(ws + 94502912);    // 4 MB bf16
  unsigned short* WpT   = (unsigned short*)(ws + 98697216);    // 2 MB bf16

  dim3 blk(256);
  transpose_k<<<dim3(32, 32), blk, 0, stream>>>(Wq,  WqT,  1024, 1024);
  transpose_k<<<dim3(64, 32), blk, 0, stream>>>(Wkv, WkvT, 1024, 2048);
  transpose_k<<<dim3(32, 32), blk, 0, stream>>>(Wp,  WpT,  1024, 1024);

  ss_init_k<<<dim3(128), blk, 0, stream>>>(bssq, bssk, ss_q, ss_kv);
  ss2_k<<<dim3(8, 16, 2), blk, 0, stream>>>(tvec, Wssq, Wssk, ss_q, ss_kv);

  ada_ln_k<<<dim3(16384), blk, 0, stream>>>(x_q,  ss_q,  xq,  2048);
  ada_ln_k<<<dim3(4096),  blk, 0, stream>>>(x_kv, ss_kv, xkv, 512);

  gemm_bt_k<<<dim3(8, 128), blk, 0, stream>>>(xq,  WqT,  bq,  nullptr, qbuf, nullptr, nullptr,
                                              16384, 1024, 1024, 0);
  gemm_bt_k<<<dim3(16, 32), blk, 0, stream>>>(xkv, WkvT, bkv, nullptr, kbuf, nullptr, vTbuf,
                                              4096, 2048, 1024, 2);

  attn_k<<<dim3(16, 16, 8), blk, 0, stream>>>(qbuf, kbuf, vTbuf, xq);

  gemm_bt_k<<<dim3(8, 128), blk, 0, stream>>>(xq, WpT, bp, x_q, nullptr, (float*)d_out, nullptr,
                                              16384, 1024, 1024, 1);
}

// Round 2
// 433.554 us; speedup vs baseline: 1.0174x; 1.0144x over previous
//
#include <hip/hip_runtime.h>
#include <hip/hip_bf16.h>
#include <stdint.h>

typedef __attribute__((ext_vector_type(8))) short bf16x8;
typedef __attribute__((ext_vector_type(4))) float f32x4;
typedef __attribute__((ext_vector_type(4))) _Float16 f16x4;
typedef __attribute__((ext_vector_type(8))) _Float16 f16x8;
typedef __attribute__((ext_vector_type(4))) unsigned short u16x4;

__device__ __forceinline__ float b2f(unsigned short u){
  union { unsigned int i; float f; } x; x.i = ((unsigned int)u) << 16; return x.f;
}
__device__ __forceinline__ unsigned short f2b(float f){
  union { float f; unsigned int i; } x; x.f = f;
  unsigned int r = x.i + 0x7fffu + ((x.i >> 16) & 1u);
  return (unsigned short)(r >> 16);
}

__device__ __forceinline__ void gld_lds16(const void* g, void* l){
  __builtin_amdgcn_global_load_lds((const __attribute__((address_space(1))) unsigned int*)g,
                                   (__attribute__((address_space(3))) unsigned int*)l,
                                   16, 0, 0);
}

// ---------------- transpose + fp32->bf16: in (R x C) fp32 -> out (C x R) bf16 ----------------
__global__ __launch_bounds__(256) void transpose_k(const float* __restrict__ in,
                                                   unsigned short* __restrict__ out,
                                                   int R, int C){
  __shared__ unsigned short tile[32][33];
  int tx = threadIdx.x & 31, ty = threadIdx.x >> 5;
  int r0 = blockIdx.y * 32, c0 = blockIdx.x * 32;
#pragma unroll
  for (int t = 0; t < 4; ++t)
    tile[ty + t*8][tx] = f2b(in[(size_t)(r0 + ty + t*8) * C + c0 + tx]);
  __syncthreads();
#pragma unroll
  for (int t = 0; t < 4; ++t)
    out[(size_t)(c0 + ty + t*8) * R + r0 + tx] = tile[tx][ty + t*8];
}

// ---------------- ss init: ss[which][b][j] = bias_which[j] ----------------
__global__ __launch_bounds__(256) void ss_init_k(const float* __restrict__ bssq,
                                                 const float* __restrict__ bssk,
                                                 float* __restrict__ ss_q,
                                                 float* __restrict__ ss_kv){
  int idx = blockIdx.x*256 + threadIdx.x;          // 0..32767
  int which = idx >> 14, rem = idx & 16383;
  int j = rem & 2047;
  if (which) ss_kv[rem] = bssk[j];
  else       ss_q[rem]  = bssq[j];
}

// ---------------- ss main: ss[which][b][col] += sum_k silu(c[b][k]) * W[k][col] ----------------
__global__ __launch_bounds__(256) void ss2_k(const float* __restrict__ tvec,
                                             const float* __restrict__ Wssq,
                                             const float* __restrict__ Wssk,
                                             float* __restrict__ ss_q,
                                             float* __restrict__ ss_kv){
  const int which = blockIdx.z;
  const float* W = which ? Wssk : Wssq;
  float* ss = which ? ss_kv : ss_q;
  const int col = blockIdx.x*256 + threadIdx.x;
  const int k0 = blockIdx.y*64;

  __shared__ float sl[8][64];
  int idx = threadIdx.x;
#pragma unroll
  for (int t = 0; t < 2; ++t){
    int i = idx + t*256;
    int b = i >> 6, k = i & 63;
    float c = tvec[b*1024 + k0 + k];
    sl[b][k] = c / (1.f + __expf(-c));
  }
  __syncthreads();

  float acc[8] = {0.f,0.f,0.f,0.f,0.f,0.f,0.f,0.f};
#pragma unroll 8
  for (int k = 0; k < 64; ++k){
    float w = W[(size_t)(k0 + k)*2048 + col];
#pragma unroll
    for (int b = 0; b < 8; ++b) acc[b] += sl[b][k] * w;
  }
#pragma unroll
  for (int b = 0; b < 8; ++b)
    atomicAdd(&ss[b*2048 + col], acc[b]);
}

// ---------------- adaptive layernorm (fp32 in, bf16 out): per row of H=1024 ----------------
__global__ __launch_bounds__(256) void ada_ln_k(const float* __restrict__ x,
                                                const float* __restrict__ ss,
                                                unsigned short* __restrict__ out,
                                                int L){
  int row = blockIdx.x;
  int b = row / L;
  const float* xr = x + (size_t)row * 1024;
  int tid = threadIdx.x;
  float4 v = *(const float4*)&xr[tid*4];
  float s = v.x + v.y + v.z + v.w;
  __shared__ float red[4];
#pragma unroll
  for (int o = 32; o > 0; o >>= 1) s += __shfl_xor(s, o, 64);
  if ((tid & 63) == 0) red[tid >> 6] = s;
  __syncthreads();
  float mu = (red[0]+red[1]+red[2]+red[3]) * (1.f/1024.f);
  __syncthreads();
  float vs = (v.x-mu)*(v.x-mu) + (v.y-mu)*(v.y-mu) + (v.z-mu)*(v.z-mu) + (v.w-mu)*(v.w-mu);
#pragma unroll
  for (int o = 32; o > 0; o >>= 1) vs += __shfl_xor(vs, o, 64);
  if ((tid & 63) == 0) red[tid >> 6] = vs;
  __syncthreads();
  float var = (red[0]+red[1]+red[2]+red[3]) * (1.f/1024.f);
  float inv = rsqrtf(var + 1e-5f);
  const float* sb = ss + (size_t)b*2048;
  float4 sc = *(const float4*)&sb[tid*4];
  float4 bi = *(const float4*)&sb[1024 + tid*4];
  u16x4 o4;
  o4[0] = f2b((1.f + sc.x) * ((v.x-mu)*inv) + bi.x);
  o4[1] = f2b((1.f + sc.y) * ((v.y-mu)*inv) + bi.y);
  o4[2] = f2b((1.f + sc.z) * ((v.z-mu)*inv) + bi.z);
  o4[3] = f2b((1.f + sc.w) * ((v.w-mu)*inv) + bi.w);
  *(u16x4*)&out[(size_t)row*1024 + tid*4] = o4;
}

// ---------------- GEMM 128x128, 2-phase dbuf: C = A(MxK,bf16) @ BT(NxK,bf16)^T + bias ----------------
// mode 0: bf16 out to Cb (stride 1024)
// mode 1: fp32 out to Cf (stride N) + fp32 residual resf
// mode 2: kv split: col<1024 -> bf16 Cb (stride 1024); col>=1024 -> f16 vT[b][d][l]
__global__ __launch_bounds__(256) void gemm_bt_k(const unsigned short* __restrict__ A,
                                                 const unsigned short* __restrict__ BT,
                                                 const float* __restrict__ bias,
                                                 const float* __restrict__ resf,
                                                 unsigned short* __restrict__ Cb,
                                                 float* __restrict__ Cf,
                                                 _Float16* __restrict__ vT,
                                                 int M, int N, int K, int mode){
  __shared__ __attribute__((aligned(16))) unsigned short As[2][128*64];
  __shared__ __attribute__((aligned(16))) unsigned short Bs[2][128*64];
  const int tid = threadIdx.x;
  const int wave = tid >> 6, lane = tid & 63;
  const int lm = lane & 15, quad = lane >> 4;

  // ---- XCD swizzle: lid -> tile so that XCD k gets a contiguous chunk ----
  const int gx = gridDim.x;
  const int nwg = gx * gridDim.y;            // 512 (KV): %8==0
  const int lid = blockIdx.y * gx + blockIdx.x;
  const int chunk = nwg >> 3;
  const int tile = (lid & 7) * chunk + (lid >> 3);
  const int m0 = (tile / gx) * 128, n0 = (tile % gx) * 128;

  const int wm = (wave >> 1) * 64, wn = (wave & 1) * 64;
  f32x4 acc[4][4];
#pragma unroll
  for (int i = 0; i < 4; ++i)
#pragma unroll
    for (int j = 0; j < 4; ++j) acc[i][j] = (f32x4){0.f,0.f,0.f,0.f};

  // staging map: c = r*256+tid in [0,1024): row = c>>3, colseg = (c&7)*8
  int rowc[4], colc[4];
#pragma unroll
  for (int r = 0; r < 4; ++r){
    int c = r*256 + tid;
    rowc[r] = c >> 3; colc[r] = (c & 7) * 8;
  }

#define STAGE128(buf, kk)                                                              \
  {                                                                                    \
    _Pragma("unroll")                                                                  \
    for (int r = 0; r < 4; ++r)                                                        \
      gld_lds16(&A[(size_t)(m0 + rowc[r])*K + (kk) + colc[r]], &As[buf][(r*256 + tid)*8]); \
    _Pragma("unroll")                                                                  \
    for (int r = 0; r < 4; ++r)                                                        \
      gld_lds16(&BT[(size_t)(n0 + rowc[r])*K + (kk) + colc[r]], &Bs[buf][(r*256 + tid)*8]); \
  }

  const int NT = K >> 6;
  STAGE128(0, 0);
  __syncthreads();                 // vmcnt(0)+lgkmcnt(0)+barrier: buf0 staged

  int cur = 0;
  for (int t = 0; t < NT; ++t){
    if (t + 1 < NT) STAGE128(cur ^ 1, (t + 1) << 6);   // overlaps with compute below
#pragma unroll
    for (int ks = 0; ks < 2; ++ks){
      bf16x8 af[4], bfr[4];
#pragma unroll
      for (int i = 0; i < 4; ++i)
        af[i] = *(bf16x8*)&As[cur][(wm + i*16 + lm)*64 + ks*32 + quad*8];
#pragma unroll
      for (int j = 0; j < 4; ++j)
        bfr[j] = *(bf16x8*)&Bs[cur][(wn + j*16 + lm)*64 + ks*32 + quad*8];
#pragma unroll
      for (int i = 0; i < 4; ++i)
#pragma unroll
        for (int j = 0; j < 4; ++j)
          acc[i][j] = __builtin_amdgcn_mfma_f32_16x16x32_bf16(af[i], bfr[j], acc[i][j], 0, 0, 0);
    }
    __syncthreads();               // drains this iter's stage; next buf ready
    cur ^= 1;
  }
#undef STAGE128

  if (mode == 2 && n0 >= 1024){
#pragma unroll
    for (int j = 0; j < 4; ++j){
      int col = n0 + wn + j*16 + lm;
      int d = col - 1024;
      float bv = bias[col];
#pragma unroll
      for (int i = 0; i < 4; ++i){
        int rowb = m0 + wm + i*16 + quad*4;
        int brow = rowb >> 9, l = rowb & 511;
        f16x4 h4;
#pragma unroll
        for (int p = 0; p < 4; ++p) h4[p] = (_Float16)(acc[i][j][p] + bv);
        *(f16x4*)&vT[((size_t)brow*1024 + d)*512 + l] = h4;
      }
    }
    return;
  }

#pragma unroll
  for (int j = 0; j < 4; ++j){
    int col = n0 + wn + j*16 + lm;
    float bv = bias[col];
#pragma unroll
    for (int i = 0; i < 4; ++i){
#pragma unroll
      for (int p = 0; p < 4; ++p){
        int row = m0 + wm + i*16 + quad*4 + p;
        float v = acc[i][j][p] + bv;
        if (mode == 1){
          Cf[(size_t)row*N + col] = v + resf[(size_t)row*N + col];
        } else {
          Cb[(size_t)row*1024 + col] = f2b(v);
        }
      }
    }
  }
}

// ---------------- GEMM 256x256, 8 waves, 2-phase dbuf (Q-proj / P-proj) ----------------
// mode 0: bf16 out to Cb (stride 1024); mode 1: fp32 out + residual
__global__ __launch_bounds__(512) void gemm256_k(const unsigned short* __restrict__ A,
                                                 const unsigned short* __restrict__ BT,
                                                 const float* __restrict__ bias,
                                                 const float* __restrict__ resf,
                                                 unsigned short* __restrict__ Cb,
                                                 float* __restrict__ Cf,
                                                 int M, int N, int K, int mode){
  __shared__ __attribute__((aligned(16))) unsigned short As[2][256*64];
  __shared__ __attribute__((aligned(16))) unsigned short Bs[2][256*64];
  const int tid = threadIdx.x;               // 0..511
  const int wave = tid >> 6, lane = tid & 63;
  const int lm = lane & 15, quad = lane >> 4;

  // XCD swizzle (nwg % 8 == 0 for all our grids)
  const int gx = gridDim.x;
  const int nwg = gx * gridDim.y;
  const int lid = blockIdx.y * gx + blockIdx.x;
  const int chunk = nwg >> 3;
  const int tile = (lid & 7) * chunk + (lid >> 3);
  const int m0 = (tile / gx) * 256, n0 = (tile % gx) * 256;

  const int wm = (wave >> 2) * 128, wn = (wave & 3) * 64;   // 2x4 wave grid

  f32x4 acc[8][4];
#pragma unroll
  for (int i = 0; i < 8; ++i)
#pragma unroll
    for (int j = 0; j < 4; ++j) acc[i][j] = (f32x4){0.f,0.f,0.f,0.f};

  // staging map: c = r*512+tid in [0,2048): row = c>>3, colseg = (c&7)*8; LDS off = c*8 elems
  int rowc[4], colc[4];
#pragma unroll
  for (int r = 0; r < 4; ++r){
    int c = r*512 + tid;
    rowc[r] = c >> 3; colc[r] = (c & 7) * 8;
  }

#define STAGE256(buf, kk)                                                              \
  {                                                                                    \
    _Pragma("unroll")                                                                  \
    for (int r = 0; r < 4; ++r)                                                        \
      gld_lds16(&A[(size_t)(m0 + rowc[r])*K + (kk) + colc[r]], &As[buf][(r*512 + tid)*8]); \
    _Pragma("unroll")                                                                  \
    for (int r = 0; r < 4; ++r)                                                        \
      gld_lds16(&BT[(size_t)(n0 + rowc[r])*K + (kk) + colc[r]], &Bs[buf][(r*512 + tid)*8]); \
  }

  const int NT = K >> 6;                     // 16
  STAGE256(0, 0);
  __syncthreads();

  int cur = 0;
  for (int t = 0; t < NT; ++t){
    if (t + 1 < NT) STAGE256(cur ^ 1, (t + 1) << 6);
#pragma unroll
    for (int ks = 0; ks < 2; ++ks){
      bf16x8 af[8], bfr[4];
#pragma unroll
      for (int i = 0; i < 8; ++i)
        af[i] = *(bf16x8*)&As[cur][(wm + i*16 + lm)*64 + ks*32 + quad*8];
#pragma unroll
      for (int j = 0; j < 4; ++j)
        bfr[j] = *(bf16x8*)&Bs[cur][(wn + j*16 + lm)*64 + ks*32 + quad*8];
#pragma unroll
      for (int i = 0; i < 8; ++i)
#pragma unroll
        for (int j = 0; j < 4; ++j)
          acc[i][j] = __builtin_amdgcn_mfma_f32_16x16x32_bf16(af[i], bfr[j], acc[i][j], 0, 0, 0);
    }
    __syncthreads();
    cur ^= 1;
  }
#undef STAGE256

#pragma unroll
  for (int j = 0; j < 4; ++j){
    int col = n0 + wn + j*16 + lm;
    float bv = bias[col];
#pragma unroll
    for (int i = 0; i < 8; ++i){
#pragma unroll
      for (int p = 0; p < 4; ++p){
        int row = m0 + wm + i*16 + quad*4 + p;
        float v = acc[i][j][p] + bv;
        if (mode == 1){
          Cf[(size_t)row*N + col] = v + resf[(size_t)row*N + col];
        } else {
          Cb[(size_t)row*1024 + col] = f2b(v);
        }
      }
    }
  }
}

// ---------------- attention v5: S^T + online softmax + LDS-staged K/V tiles ----------------
// XCD swizzle: each XCD owns 16 consecutive (b,h) head-slices (2 MB K/V resident per L2)
__global__ __launch_bounds__(256) void attn_k(const unsigned short* __restrict__ q,
                                              const unsigned short* __restrict__ kbuf,
                                              const _Float16* __restrict__ vT,
                                              unsigned short* __restrict__ out){
  const int lid = (blockIdx.z * gridDim.y + blockIdx.y) * gridDim.x + blockIdx.x; // 0..2047
  const int tile = (lid & 7) * 256 + (lid >> 3);
  const int qb = tile & 15, h = (tile >> 4) & 15, b = tile >> 8;
  const int tid = threadIdx.x;
  const int wave = tid >> 6, lane = tid & 63;
  const int lm = lane & 15, quad = lane >> 4;
  const int q0 = qb * 128;

  __shared__ __attribute__((aligned(16))) unsigned short Ks[64*72];
  __shared__ __attribute__((aligned(16))) _Float16      Vs[64*72];

  bf16x8 qf[2][2];
#pragma unroll
  for (int u = 0; u < 2; ++u){
    const unsigned short* qrow = q + ((size_t)b*2048 + q0 + wave*32 + u*16 + lm)*1024 + h*64;
    qf[u][0] = *(const bf16x8*)&qrow[quad*8];
    qf[u][1] = *(const bf16x8*)&qrow[32 + quad*8];
  }

  const unsigned short* kb = kbuf + ((size_t)b*512)*1024 + h*64;
  const _Float16*       vb = vT + ((size_t)b*1024 + h*64)*512;

  f32x4 oacc[2][4];
#pragma unroll
  for (int u = 0; u < 2; ++u)
#pragma unroll
    for (int nt = 0; nt < 4; ++nt) oacc[u][nt] = (f32x4){0.f,0.f,0.f,0.f};
  float m_run[2] = {-1e30f, -1e30f}, l_run[2] = {0.f, 0.f};

  const int srow = tid >> 3, scol = (tid & 7) * 8;

  for (int kt = 0; kt < 8; ++kt){
    const int l0 = kt * 64;
    __syncthreads();
#pragma unroll
    for (int r = 0; r < 2; ++r){
      int row = r*32 + srow;
      *(bf16x8*)&Ks[row*72 + scol] = *(const bf16x8*)&kb[(size_t)(l0 + row)*1024 + scol];
      *(f16x8*)&Vs[row*72 + scol]  = *(const f16x8*)&vb[(size_t)row*512 + l0 + scol];
    }
    __syncthreads();

    f32x4 sacc[2][4];
#pragma unroll
    for (int u = 0; u < 2; ++u)
#pragma unroll
      for (int s = 0; s < 4; ++s) sacc[u][s] = (f32x4){0.f,0.f,0.f,0.f};
#pragma unroll
    for (int s = 0; s < 4; ++s){
      bf16x8 kf0 = *(bf16x8*)&Ks[(s*16 + lm)*72 + quad*8];
      bf16x8 kf1 = *(bf16x8*)&Ks[(s*16 + lm)*72 + 32 + quad*8];
#pragma unroll
      for (int u = 0; u < 2; ++u){
        sacc[u][s] = __builtin_amdgcn_mfma_f32_16x16x32_bf16(kf0, qf[u][0], sacc[u][s], 0, 0, 0);
        sacc[u][s] = __builtin_amdgcn_mfma_f32_16x16x32_bf16(kf1, qf[u][1], sacc[u][s], 0, 0, 0);
      }
    }

    f16x4 pf[2][4];
#pragma unroll
    for (int u = 0; u < 2; ++u){
      float tm = -1e30f;
#pragma unroll
      for (int s = 0; s < 4; ++s)
#pragma unroll
        for (int p = 0; p < 4; ++p) tm = fmaxf(tm, sacc[u][s][p]);
      tm = fmaxf(tm, __shfl_xor(tm, 16, 64));
      tm = fmaxf(tm, __shfl_xor(tm, 32, 64));
      float m_new = fmaxf(m_run[u], tm * 0.125f);
      float alpha = __expf(m_run[u] - m_new);
      m_run[u] = m_new;
      l_run[u] *= alpha;
      float ap[4];
#pragma unroll
      for (int p = 0; p < 4; ++p) ap[p] = __shfl(alpha, quad*4 + p, 64);
#pragma unroll
      for (int nt = 0; nt < 4; ++nt){
        oacc[u][nt][0] *= ap[0]; oacc[u][nt][1] *= ap[1];
        oacc[u][nt][2] *= ap[2]; oacc[u][nt][3] *= ap[3];
      }
#pragma unroll
      for (int s = 0; s < 4; ++s)
#pragma unroll
        for (int p = 0; p < 4; ++p){
          float e = __expf(sacc[u][s][p] * 0.125f - m_new);
          l_run[u] += e;
          pf[u][s][p] = (_Float16)e;
        }
    }

#pragma unroll
    for (int s = 0; s < 4; ++s){
#pragma unroll
      for (int nt = 0; nt < 4; ++nt){
        f16x4 vf = *(const f16x4*)&Vs[(size_t)(nt*16 + lm)*72 + s*16 + quad*4];
#pragma unroll
        for (int u = 0; u < 2; ++u)
          oacc[u][nt] = __builtin_amdgcn_mfma_f32_16x16x16f16(pf[u][s], vf, oacc[u][nt], 0, 0, 0);
      }
    }
  }

#pragma unroll
  for (int u = 0; u < 2; ++u){
    float lr = l_run[u];
    lr += __shfl_xor(lr, 16, 64);
    lr += __shfl_xor(lr, 32, 64);
    float rinv = 1.f / lr;
    float rp[4];
#pragma unroll
    for (int p = 0; p < 4; ++p) rp[p] = __shfl(rinv, quad*4 + p, 64);
    const size_t obase = ((size_t)b*2048 + q0 + wave*32 + u*16) * 1024 + h*64;
#pragma unroll
    for (int nt = 0; nt < 4; ++nt)
#pragma unroll
      for (int p = 0; p < 4; ++p){
        int row = quad*4 + p;
        out[obase + (size_t)row*1024 + nt*16 + lm] = f2b(oacc[u][nt][p] * rp[p]);
      }
  }
}

extern "C" void kernel_launch(void* const* d_in, const int* in_sizes, int n_in,
                              void* d_out, int out_size, void* d_ws, size_t ws_size,
                              hipStream_t stream){
  const float* x_q  = (const float*)d_in[0];
  const float* x_kv = (const float*)d_in[1];
  const float* tvec = (const float*)d_in[2];
  const float* Wq   = (const float*)d_in[3];
  const float* bq   = (const float*)d_in[4];
  const float* Wkv  = (const float*)d_in[5];
  const float* bkv  = (const float*)d_in[6];
  const float* Wp   = (const float*)d_in[7];
  const float* bp   = (const float*)d_in[8];
  const float* Wssq = (const float*)d_in[9];
  const float* bssq = (const float*)d_in[10];
  const float* Wssk = (const float*)d_in[11];
  const float* bssk = (const float*)d_in[12];

  char* ws = (char*)d_ws;
  float*          ss_q  = (float*)(ws + 0);                    // 64 KB
  float*          ss_kv = (float*)(ws + 65536);                // 64 KB
  unsigned short* xq    = (unsigned short*)(ws + 131072);      // 32 MB bf16; reused as attn out
  unsigned short* xkv   = (unsigned short*)(ws + 33685504);    // 8 MB bf16
  unsigned short* qbuf  = (unsigned short*)(ws + 42074112);    // 32 MB bf16
  unsigned short* kbuf  = (unsigned short*)(ws + 75628544);    // 8 MB bf16
  _Float16*       vTbuf = (_Float16*)     (ws + 84017152);     // 8 MB f16
  unsigned short* WqT   = (unsigned short*)(ws + 92405760);    // 2 MB bf16
  unsigned short* WkvT  = (unsigned short*)(ws + 94502912);    // 4 MB bf16
  unsigned short* WpT   = (unsigned short*)(ws + 98697216);    // 2 MB bf16

  dim3 blk(256);
  transpose_k<<<dim3(32, 32), blk, 0, stream>>>(Wq,  WqT,  1024, 1024);
  transpose_k<<<dim3(64, 32), blk, 0, stream>>>(Wkv, WkvT, 1024, 2048);
  transpose_k<<<dim3(32, 32), blk, 0, stream>>>(Wp,  WpT,  1024, 1024);

  ss_init_k<<<dim3(128), blk, 0, stream>>>(bssq, bssk, ss_q, ss_kv);
  ss2_k<<<dim3(8, 16, 2), blk, 0, stream>>>(tvec, Wssq, Wssk, ss_q, ss_kv);

  ada_ln_k<<<dim3(16384), blk, 0, stream>>>(x_q,  ss_q,  xq,  2048);
  ada_ln_k<<<dim3(4096),  blk, 0, stream>>>(x_kv, ss_kv, xkv, 512);

  gemm256_k<<<dim3(4, 64), dim3(512), 0, stream>>>(xq, WqT, bq, nullptr, qbuf, nullptr,
                                                   16384, 1024, 1024, 0);
  gemm_bt_k<<<dim3(16, 32), blk, 0, stream>>>(xkv, WkvT, bkv, nullptr, kbuf, nullptr, vTbuf,
                                              4096, 2048, 1024, 2);

  attn_k<<<dim3(16, 16, 8), blk, 0, stream>>>(qbuf, kbuf, vTbuf, xq);

  gemm256_k<<<dim3(4, 64), dim3(512), 0, stream>>>(xq, WpT, bp, x_q, nullptr, (float*)d_out,
                                                   16384, 1024, 1024, 1);
}

// Round 4
// 417.434 us; speedup vs baseline: 1.0567x; 1.0386x over previous
//
#include <hip/hip_runtime.h>
#include <hip/hip_bf16.h>
#include <stdint.h>

typedef __attribute__((ext_vector_type(8))) short bf16x8;
typedef __attribute__((ext_vector_type(4))) float f32x4;
typedef __attribute__((ext_vector_type(4))) _Float16 f16x4;
typedef __attribute__((ext_vector_type(8))) _Float16 f16x8;
typedef __attribute__((ext_vector_type(4))) unsigned short u16x4;

__device__ __forceinline__ float b2f(unsigned short u){
  union { unsigned int i; float f; } x; x.i = ((unsigned int)u) << 16; return x.f;
}
__device__ __forceinline__ unsigned short f2b(float f){
  union { float f; unsigned int i; } x; x.f = f;
  unsigned int r = x.i + 0x7fffu + ((x.i >> 16) & 1u);
  return (unsigned short)(r >> 16);
}

__device__ __forceinline__ void gld_lds16(const void* g, void* l){
  __builtin_amdgcn_global_load_lds((const __attribute__((address_space(1))) unsigned int*)g,
                                   (__attribute__((address_space(3))) unsigned int*)l,
                                   16, 0, 0);
}

// ---------------- transpose + fp32->bf16: in (R x C) fp32 -> out (C x R) bf16 ----------------
__global__ __launch_bounds__(256) void transpose_k(const float* __restrict__ in,
                                                   unsigned short* __restrict__ out,
                                                   int R, int C){
  __shared__ unsigned short tile[32][33];
  int tx = threadIdx.x & 31, ty = threadIdx.x >> 5;
  int r0 = blockIdx.y * 32, c0 = blockIdx.x * 32;
#pragma unroll
  for (int t = 0; t < 4; ++t)
    tile[ty + t*8][tx] = f2b(in[(size_t)(r0 + ty + t*8) * C + c0 + tx]);
  __syncthreads();
#pragma unroll
  for (int t = 0; t < 4; ++t)
    out[(size_t)(c0 + ty + t*8) * R + r0 + tx] = tile[tx][ty + t*8];
}

// ---------------- ss init: ss[which][b][j] = bias_which[j] ----------------
__global__ __launch_bounds__(256) void ss_init_k(const float* __restrict__ bssq,
                                                 const float* __restrict__ bssk,
                                                 float* __restrict__ ss_q,
                                                 float* __restrict__ ss_kv){
  int idx = blockIdx.x*256 + threadIdx.x;          // 0..32767
  int which = idx >> 14, rem = idx & 16383;
  int j = rem & 2047;
  if (which) ss_kv[rem] = bssk[j];
  else       ss_q[rem]  = bssq[j];
}

// ---------------- ss main: ss[which][b][col] += sum_k silu(c[b][k]) * W[k][col] ----------------
__global__ __launch_bounds__(256) void ss2_k(const float* __restrict__ tvec,
                                             const float* __restrict__ Wssq,
                                             const float* __restrict__ Wssk,
                                             float* __restrict__ ss_q,
                                             float* __restrict__ ss_kv){
  const int which = blockIdx.z;
  const float* W = which ? Wssk : Wssq;
  float* ss = which ? ss_kv : ss_q;
  const int col = blockIdx.x*256 + threadIdx.x;
  const int k0 = blockIdx.y*64;

  __shared__ float sl[8][64];
  int idx = threadIdx.x;
#pragma unroll
  for (int t = 0; t < 2; ++t){
    int i = idx + t*256;
    int b = i >> 6, k = i & 63;
    float c = tvec[b*1024 + k0 + k];
    sl[b][k] = c / (1.f + __expf(-c));
  }
  __syncthreads();

  float acc[8] = {0.f,0.f,0.f,0.f,0.f,0.f,0.f,0.f};
#pragma unroll 8
  for (int k = 0; k < 64; ++k){
    float w = W[(size_t)(k0 + k)*2048 + col];
#pragma unroll
    for (int b = 0; b < 8; ++b) acc[b] += sl[b][k] * w;
  }
#pragma unroll
  for (int b = 0; b < 8; ++b)
    atomicAdd(&ss[b*2048 + col], acc[b]);
}

// ---------------- adaptive layernorm (fp32 in, bf16 out): per row of H=1024 ----------------
__global__ __launch_bounds__(256) void ada_ln_k(const float* __restrict__ x,
                                                const float* __restrict__ ss,
                                                unsigned short* __restrict__ out,
                                                int L){
  int row = blockIdx.x;
  int b = row / L;
  const float* xr = x + (size_t)row * 1024;
  int tid = threadIdx.x;
  float4 v = *(const float4*)&xr[tid*4];
  float s = v.x + v.y + v.z + v.w;
  __shared__ float red[4];
#pragma unroll
  for (int o = 32; o > 0; o >>= 1) s += __shfl_xor(s, o, 64);
  if ((tid & 63) == 0) red[tid >> 6] = s;
  __syncthreads();
  float mu = (red[0]+red[1]+red[2]+red[3]) * (1.f/1024.f);
  __syncthreads();
  float vs = (v.x-mu)*(v.x-mu) + (v.y-mu)*(v.y-mu) + (v.z-mu)*(v.z-mu) + (v.w-mu)*(v.w-mu);
#pragma unroll
  for (int o = 32; o > 0; o >>= 1) vs += __shfl_xor(vs, o, 64);
  if ((tid & 63) == 0) red[tid >> 6] = vs;
  __syncthreads();
  float var = (red[0]+red[1]+red[2]+red[3]) * (1.f/1024.f);
  float inv = rsqrtf(var + 1e-5f);
  const float* sb = ss + (size_t)b*2048;
  float4 sc = *(const float4*)&sb[tid*4];
  float4 bi = *(const float4*)&sb[1024 + tid*4];
  u16x4 o4;
  o4[0] = f2b((1.f + sc.x) * ((v.x-mu)*inv) + bi.x);
  o4[1] = f2b((1.f + sc.y) * ((v.y-mu)*inv) + bi.y);
  o4[2] = f2b((1.f + sc.z) * ((v.z-mu)*inv) + bi.z);
  o4[3] = f2b((1.f + sc.w) * ((v.w-mu)*inv) + bi.w);
  *(u16x4*)&out[(size_t)row*1024 + tid*4] = o4;
}

// ---------------- GEMM 128x128, counted-vmcnt dbuf pipeline ----------------
// mode 0: bf16 out to Cb (stride 1024)
// mode 1: fp32 out to Cf (stride N) + fp32 residual resf
// mode 2: kv split: col<1024 -> bf16 Cb (stride 1024); col>=1024 -> f16 vT[b][d][l]
__global__ __launch_bounds__(256) void gemm_bt_k(const unsigned short* __restrict__ A,
                                                 const unsigned short* __restrict__ BT,
                                                 const float* __restrict__ bias,
                                                 const float* __restrict__ resf,
                                                 unsigned short* __restrict__ Cb,
                                                 float* __restrict__ Cf,
                                                 _Float16* __restrict__ vT,
                                                 int M, int N, int K, int mode){
  __shared__ __attribute__((aligned(16))) unsigned short As[2][128*64];
  __shared__ __attribute__((aligned(16))) unsigned short Bs[2][128*64];
  const int tid = threadIdx.x;
  const int wave = tid >> 6, lane = tid & 63;
  const int lm = lane & 15, quad = lane >> 4;

  // ---- XCD swizzle: lid -> tile so that XCD k gets a contiguous chunk ----
  const int gx = gridDim.x;
  const int nwg = gx * gridDim.y;            // %8==0
  const int lid = blockIdx.y * gx + blockIdx.x;
  const int chunk = nwg >> 3;
  const int tile = (lid & 7) * chunk + (lid >> 3);
  const int m0 = (tile / gx) * 128, n0 = (tile % gx) * 128;

  const int wm = (wave >> 1) * 64, wn = (wave & 1) * 64;
  f32x4 acc[4][4];
#pragma unroll
  for (int i = 0; i < 4; ++i)
#pragma unroll
    for (int j = 0; j < 4; ++j) acc[i][j] = (f32x4){0.f,0.f,0.f,0.f};

  // staging map: c = r*256+tid in [0,1024): row = c>>3, colseg = (c&7)*8
  int rowc[4], colc[4];
#pragma unroll
  for (int r = 0; r < 4; ++r){
    int c = r*256 + tid;
    rowc[r] = c >> 3; colc[r] = (c & 7) * 8;
  }

#define STAGE128(buf, kk)                                                              \
  {                                                                                    \
    _Pragma("unroll")                                                                  \
    for (int r = 0; r < 4; ++r)                                                        \
      gld_lds16(&A[(size_t)(m0 + rowc[r])*K + (kk) + colc[r]], &As[buf][(r*256 + tid)*8]); \
    _Pragma("unroll")                                                                  \
    for (int r = 0; r < 4; ++r)                                                        \
      gld_lds16(&BT[(size_t)(n0 + rowc[r])*K + (kk) + colc[r]], &Bs[buf][(r*256 + tid)*8]); \
  }

  const int NT = K >> 6;
  STAGE128(0, 0);
  STAGE128(1, 64);
  asm volatile("s_waitcnt vmcnt(8)" ::: "memory");   // tile0 landed; tile1 in flight
  __builtin_amdgcn_s_barrier();

  for (int t = 0; t < NT; ++t){
    const int cur = t & 1;
#pragma unroll
    for (int ks = 0; ks < 2; ++ks){
      bf16x8 af[4], bfr[4];
#pragma unroll
      for (int i = 0; i < 4; ++i)
        af[i] = *(bf16x8*)&As[cur][(wm + i*16 + lm)*64 + ks*32 + quad*8];
#pragma unroll
      for (int j = 0; j < 4; ++j)
        bfr[j] = *(bf16x8*)&Bs[cur][(wn + j*16 + lm)*64 + ks*32 + quad*8];
#pragma unroll
      for (int i = 0; i < 4; ++i)
#pragma unroll
        for (int j = 0; j < 4; ++j)
          acc[i][j] = __builtin_amdgcn_mfma_f32_16x16x32_bf16(af[i], bfr[j], acc[i][j], 0, 0, 0);
    }
    if (t + 1 < NT){
      __builtin_amdgcn_s_barrier();                  // all waves done reading buf[cur]
      if (t + 2 < NT){
        STAGE128(cur, (t + 2) << 6);                 // refill freed buffer
        asm volatile("s_waitcnt vmcnt(8)" ::: "memory");  // tile t+1 landed
      } else {
        asm volatile("s_waitcnt vmcnt(0)" ::: "memory");
      }
      __builtin_amdgcn_s_barrier();                  // block-wide: tile t+1 ready
    }
  }
#undef STAGE128

  if (mode == 2 && n0 >= 1024){
#pragma unroll
    for (int j = 0; j < 4; ++j){
      int col = n0 + wn + j*16 + lm;
      int d = col - 1024;
      float bv = bias[col];
#pragma unroll
      for (int i = 0; i < 4; ++i){
        int rowb = m0 + wm + i*16 + quad*4;
        int brow = rowb >> 9, l = rowb & 511;
        f16x4 h4;
#pragma unroll
        for (int p = 0; p < 4; ++p) h4[p] = (_Float16)(acc[i][j][p] + bv);
        *(f16x4*)&vT[((size_t)brow*1024 + d)*512 + l] = h4;
      }
    }
    return;
  }

#pragma unroll
  for (int j = 0; j < 4; ++j){
    int col = n0 + wn + j*16 + lm;
    float bv = bias[col];
#pragma unroll
    for (int i = 0; i < 4; ++i){
#pragma unroll
      for (int p = 0; p < 4; ++p){
        int row = m0 + wm + i*16 + quad*4 + p;
        float v = acc[i][j][p] + bv;
        if (mode == 1){
          Cf[(size_t)row*N + col] = v + resf[(size_t)row*N + col];
        } else {
          Cb[(size_t)row*1024 + col] = f2b(v);
        }
      }
    }
  }
}

// ---------------- GEMM 256x256, 8 waves, counted-vmcnt dbuf + T2 XOR-swizzle ----------------
// LDS dest is linear (gld_lds requirement); swizzle is applied by permuting the
// GLOBAL source chunk (chunk' = chunk ^ (row&7), within one 128B row -> coalescing
// unchanged) and reading LDS at chunk = (ks*4+quad) ^ (lm&7). 16-way conflict -> 2-way (free).
// mode 0: bf16 out to Cb (stride 1024); mode 1: fp32 out + residual
__global__ __launch_bounds__(512) void gemm256_k(const unsigned short* __restrict__ A,
                                                 const unsigned short* __restrict__ BT,
                                                 const float* __restrict__ bias,
                                                 const float* __restrict__ resf,
                                                 unsigned short* __restrict__ Cb,
                                                 float* __restrict__ Cf,
                                                 int M, int N, int K, int mode){
  __shared__ __attribute__((aligned(16))) unsigned short As[2][256*64];
  __shared__ __attribute__((aligned(16))) unsigned short Bs[2][256*64];
  const int tid = threadIdx.x;               // 0..511
  const int wave = tid >> 6, lane = tid & 63;
  const int lm = lane & 15, quad = lane >> 4;

  // XCD swizzle (nwg % 8 == 0 for all our grids)
  const int gx = gridDim.x;
  const int nwg = gx * gridDim.y;
  const int lid = blockIdx.y * gx + blockIdx.x;
  const int chunk = nwg >> 3;
  const int tile = (lid & 7) * chunk + (lid >> 3);
  const int m0 = (tile / gx) * 256, n0 = (tile % gx) * 256;

  const int wm = (wave >> 2) * 128, wn = (wave & 3) * 64;   // 2x4 wave grid

  f32x4 acc[8][4];
#pragma unroll
  for (int i = 0; i < 8; ++i)
#pragma unroll
    for (int j = 0; j < 4; ++j) acc[i][j] = (f32x4){0.f,0.f,0.f,0.f};

  // staging map: c = r*512+tid in [0,2048): row = c>>3, LDS chunk = c&7;
  // global source chunk is XOR-swizzled: src col = ((c&7) ^ (row&7))*8
  int rowc[4], colsw[4];
#pragma unroll
  for (int r = 0; r < 4; ++r){
    int c = r*512 + tid;
    rowc[r]  = c >> 3;
    colsw[r] = ((c & 7) ^ (rowc[r] & 7)) * 8;
  }

#define STAGE256(buf, kk)                                                              \
  {                                                                                    \
    _Pragma("unroll")                                                                  \
    for (int r = 0; r < 4; ++r)                                                        \
      gld_lds16(&A[(size_t)(m0 + rowc[r])*K + (kk) + colsw[r]], &As[buf][(r*512 + tid)*8]); \
    _Pragma("unroll")                                                                  \
    for (int r = 0; r < 4; ++r)                                                        \
      gld_lds16(&BT[(size_t)(n0 + rowc[r])*K + (kk) + colsw[r]], &Bs[buf][(r*512 + tid)*8]); \
  }

  const int NT = K >> 6;                     // 16
  STAGE256(0, 0);
  STAGE256(1, 64);
  asm volatile("s_waitcnt vmcnt(8)" ::: "memory");   // tile0 landed; tile1 (8 loads) in flight
  __builtin_amdgcn_s_barrier();

  const int rsw = lm & 7;                    // row&7 for this lane's fragment rows
  for (int t = 0; t < NT; ++t){
    const int cur = t & 1;
#pragma unroll
    for (int ks = 0; ks < 2; ++ks){
      const int rc = ((ks*4 + quad) ^ rsw) * 8;      // swizzled read chunk (elements)
      bf16x8 af[8], bfr[4];
#pragma unroll
      for (int i = 0; i < 8; ++i)
        af[i] = *(bf16x8*)&As[cur][(wm + i*16 + lm)*64 + rc];
#pragma unroll
      for (int j = 0; j < 4; ++j)
        bfr[j] = *(bf16x8*)&Bs[cur][(wn + j*16 + lm)*64 + rc];
#pragma unroll
      for (int i = 0; i < 8; ++i)
#pragma unroll
        for (int j = 0; j < 4; ++j)
          acc[i][j] = __builtin_amdgcn_mfma_f32_16x16x32_bf16(af[i], bfr[j], acc[i][j], 0, 0, 0);
    }
    if (t + 1 < NT){
      __builtin_amdgcn_s_barrier();                  // all waves done reading buf[cur]
      if (t + 2 < NT){
        STAGE256(cur, (t + 2) << 6);                 // refill freed buffer
        asm volatile("s_waitcnt vmcnt(8)" ::: "memory");  // tile t+1 landed; t+2 in flight
      } else {
        asm volatile("s_waitcnt vmcnt(0)" ::: "memory");
      }
      __builtin_amdgcn_s_barrier();                  // block-wide: tile t+1 ready
    }
  }
#undef STAGE256

#pragma unroll
  for (int j = 0; j < 4; ++j){
    int col = n0 + wn + j*16 + lm;
    float bv = bias[col];
#pragma unroll
    for (int i = 0; i < 8; ++i){
#pragma unroll
      for (int p = 0; p < 4; ++p){
        int row = m0 + wm + i*16 + quad*4 + p;
        float v = acc[i][j][p] + bv;
        if (mode == 1){
          Cf[(size_t)row*N + col] = v + resf[(size_t)row*N + col];
        } else {
          Cb[(size_t)row*1024 + col] = f2b(v);
        }
      }
    }
  }
}

// ---------------- attention v5: S^T + online softmax + LDS-staged K/V tiles ----------------
// XCD swizzle: each XCD owns 16 consecutive (b,h) head-slices (2 MB K/V resident per L2)
__global__ __launch_bounds__(256) void attn_k(const unsigned short* __restrict__ q,
                                              const unsigned short* __restrict__ kbuf,
                                              const _Float16* __restrict__ vT,
                                              unsigned short* __restrict__ out){
  const int lid = (blockIdx.z * gridDim.y + blockIdx.y) * gridDim.x + blockIdx.x; // 0..2047
  const int tile = (lid & 7) * 256 + (lid >> 3);
  const int qb = tile & 15, h = (tile >> 4) & 15, b = tile >> 8;
  const int tid = threadIdx.x;
  const int wave = tid >> 6, lane = tid & 63;
  const int lm = lane & 15, quad = lane >> 4;
  const int q0 = qb * 128;

  __shared__ __attribute__((aligned(16))) unsigned short Ks[64*72];
  __shared__ __attribute__((aligned(16))) _Float16      Vs[64*72];

  bf16x8 qf[2][2];
#pragma unroll
  for (int u = 0; u < 2; ++u){
    const unsigned short* qrow = q + ((size_t)b*2048 + q0 + wave*32 + u*16 + lm)*1024 + h*64;
    qf[u][0] = *(const bf16x8*)&qrow[quad*8];
    qf[u][1] = *(const bf16x8*)&qrow[32 + quad*8];
  }

  const unsigned short* kb = kbuf + ((size_t)b*512)*1024 + h*64;
  const _Float16*       vb = vT + ((size_t)b*1024 + h*64)*512;

  f32x4 oacc[2][4];
#pragma unroll
  for (int u = 0; u < 2; ++u)
#pragma unroll
    for (int nt = 0; nt < 4; ++nt) oacc[u][nt] = (f32x4){0.f,0.f,0.f,0.f};
  float m_run[2] = {-1e30f, -1e30f}, l_run[2] = {0.f, 0.f};

  const int srow = tid >> 3, scol = (tid & 7) * 8;

  for (int kt = 0; kt < 8; ++kt){
    const int l0 = kt * 64;
    __syncthreads();
#pragma unroll
    for (int r = 0; r < 2; ++r){
      int row = r*32 + srow;
      *(bf16x8*)&Ks[row*72 + scol] = *(const bf16x8*)&kb[(size_t)(l0 + row)*1024 + scol];
      *(f16x8*)&Vs[row*72 + scol]  = *(const f16x8*)&vb[(size_t)row*512 + l0 + scol];
    }
    __syncthreads();

    f32x4 sacc[2][4];
#pragma unroll
    for (int u = 0; u < 2; ++u)
#pragma unroll
      for (int s = 0; s < 4; ++s) sacc[u][s] = (f32x4){0.f,0.f,0.f,0.f};
#pragma unroll
    for (int s = 0; s < 4; ++s){
      bf16x8 kf0 = *(bf16x8*)&Ks[(s*16 + lm)*72 + quad*8];
      bf16x8 kf1 = *(bf16x8*)&Ks[(s*16 + lm)*72 + 32 + quad*8];
#pragma unroll
      for (int u = 0; u < 2; ++u){
        sacc[u][s] = __builtin_amdgcn_mfma_f32_16x16x32_bf16(kf0, qf[u][0], sacc[u][s], 0, 0, 0);
        sacc[u][s] = __builtin_amdgcn_mfma_f32_16x16x32_bf16(kf1, qf[u][1], sacc[u][s], 0, 0, 0);
      }
    }

    f16x4 pf[2][4];
#pragma unroll
    for (int u = 0; u < 2; ++u){
      float tm = -1e30f;
#pragma unroll
      for (int s = 0; s < 4; ++s)
#pragma unroll
        for (int p = 0; p < 4; ++p) tm = fmaxf(tm, sacc[u][s][p]);
      tm = fmaxf(tm, __shfl_xor(tm, 16, 64));
      tm = fmaxf(tm, __shfl_xor(tm, 32, 64));
      float m_new = fmaxf(m_run[u], tm * 0.125f);
      float alpha = __expf(m_run[u] - m_new);
      m_run[u] = m_new;
      l_run[u] *= alpha;
      float ap[4];
#pragma unroll
      for (int p = 0; p < 4; ++p) ap[p] = __shfl(alpha, quad*4 + p, 64);
#pragma unroll
      for (int nt = 0; nt < 4; ++nt){
        oacc[u][nt][0] *= ap[0]; oacc[u][nt][1] *= ap[1];
        oacc[u][nt][2] *= ap[2]; oacc[u][nt][3] *= ap[3];
      }
#pragma unroll
      for (int s = 0; s < 4; ++s)
#pragma unroll
        for (int p = 0; p < 4; ++p){
          float e = __expf(sacc[u][s][p] * 0.125f - m_new);
          l_run[u] += e;
          pf[u][s][p] = (_Float16)e;
        }
    }

#pragma unroll
    for (int s = 0; s < 4; ++s){
#pragma unroll
      for (int nt = 0; nt < 4; ++nt){
        f16x4 vf = *(const f16x4*)&Vs[(size_t)(nt*16 + lm)*72 + s*16 + quad*4];
#pragma unroll
        for (int u = 0; u < 2; ++u)
          oacc[u][nt] = __builtin_amdgcn_mfma_f32_16x16x16f16(pf[u][s], vf, oacc[u][nt], 0, 0, 0);
      }
    }
  }

#pragma unroll
  for (int u = 0; u < 2; ++u){
    float lr = l_run[u];
    lr += __shfl_xor(lr, 16, 64);
    lr += __shfl_xor(lr, 32, 64);
    float rinv = 1.f / lr;
    float rp[4];
#pragma unroll
    for (int p = 0; p < 4; ++p) rp[p] = __shfl(rinv, quad*4 + p, 64);
    const size_t obase = ((size_t)b*2048 + q0 + wave*32 + u*16) * 1024 + h*64;
#pragma unroll
    for (int nt = 0; nt < 4; ++nt)
#pragma unroll
      for (int p = 0; p < 4; ++p){
        int row = quad*4 + p;
        out[obase + (size_t)row*1024 + nt*16 + lm] = f2b(oacc[u][nt][p] * rp[p]);
      }
  }
}

extern "C" void kernel_launch(void* const* d_in, const int* in_sizes, int n_in,
                              void* d_out, int out_size, void* d_ws, size_t ws_size,
                              hipStream_t stream){
  const float* x_q  = (const float*)d_in[0];
  const float* x_kv = (const float*)d_in[1];
  const float* tvec = (const float*)d_in[2];
  const float* Wq   = (const float*)d_in[3];
  const float* bq   = (const float*)d_in[4];
  const float* Wkv  = (const float*)d_in[5];
  const float* bkv  = (const float*)d_in[6];
  const float* Wp   = (const float*)d_in[7];
  const float* bp   = (const float*)d_in[8];
  const float* Wssq = (const float*)d_in[9];
  const float* bssq = (const float*)d_in[10];
  const float* Wssk = (const float*)d_in[11];
  const float* bssk = (const float*)d_in[12];

  char* ws = (char*)d_ws;
  float*          ss_q  = (float*)(ws + 0);                    // 64 KB
  float*          ss_kv = (float*)(ws + 65536);                // 64 KB
  unsigned short* xq    = (unsigned short*)(ws + 131072);      // 32 MB bf16; reused as attn out
  unsigned short* xkv   = (unsigned short*)(ws + 33685504);    // 8 MB bf16
  unsigned short* qbuf  = (unsigned short*)(ws + 42074112);    // 32 MB bf16
  unsigned short* kbuf  = (unsigned short*)(ws + 75628544);    // 8 MB bf16
  _Float16*       vTbuf = (_Float16*)     (ws + 84017152);     // 8 MB f16
  unsigned short* WqT   = (unsigned short*)(ws + 92405760);    // 2 MB bf16
  unsigned short* WkvT  = (unsigned short*)(ws + 94502912);    // 4 MB bf16
  unsigned short* WpT   = (unsigned short*)(ws + 98697216);    // 2 MB bf16

  dim3 blk(256);
  transpose_k<<<dim3(32, 32), blk, 0, stream>>>(Wq,  WqT,  1024, 1024);
  transpose_k<<<dim3(64, 32), blk, 0, stream>>>(Wkv, WkvT, 1024, 2048);
  transpose_k<<<dim3(32, 32), blk, 0, stream>>>(Wp,  WpT,  1024, 1024);

  ss_init_k<<<dim3(128), blk, 0, stream>>>(bssq, bssk, ss_q, ss_kv);
  ss2_k<<<dim3(8, 16, 2), blk, 0, stream>>>(tvec, Wssq, Wssk, ss_q, ss_kv);

  ada_ln_k<<<dim3(16384), blk, 0, stream>>>(x_q,  ss_q,  xq,  2048);
  ada_ln_k<<<dim3(4096),  blk, 0, stream>>>(x_kv, ss_kv, xkv, 512);

  gemm256_k<<<dim3(4, 64), dim3(512), 0, stream>>>(xq, WqT, bq, nullptr, qbuf, nullptr,
                                                   16384, 1024, 1024, 0);
  gemm_bt_k<<<dim3(16, 32), blk, 0, stream>>>(xkv, WkvT, bkv, nullptr, kbuf, nullptr, vTbuf,
                                              4096, 2048, 1024, 2);

  attn_k<<<dim3(16, 16, 8), blk, 0, stream>>>(qbuf, kbuf, vTbuf, xq);

  gemm256_k<<<dim3(4, 64), dim3(512), 0, stream>>>(xq, WpT, bp, x_q, nullptr, (float*)d_out,
                                                   16384, 1024, 1024, 1);
}

// Round 9
// 415.204 us; speedup vs baseline: 1.0624x; 1.0054x over previous
//
#include <hip/hip_runtime.h>
#include <hip/hip_bf16.h>
#include <stdint.h>

typedef __attribute__((ext_vector_type(8))) short bf16x8;
typedef __attribute__((ext_vector_type(4))) float f32x4;
typedef __attribute__((ext_vector_type(4))) _Float16 f16x4;
typedef __attribute__((ext_vector_type(8))) _Float16 f16x8;
typedef __attribute__((ext_vector_type(4))) unsigned short u16x4;

__device__ __forceinline__ float b2f(unsigned short u){
  union { unsigned int i; float f; } x; x.i = ((unsigned int)u) << 16; return x.f;
}
__device__ __forceinline__ unsigned short f2b(float f){
  union { float f; unsigned int i; } x; x.f = f;
  unsigned int r = x.i + 0x7fffu + ((x.i >> 16) & 1u);
  return (unsigned short)(r >> 16);
}

__device__ __forceinline__ void gld_lds16(const void* g, void* l){
  __builtin_amdgcn_global_load_lds((const __attribute__((address_space(1))) unsigned int*)g,
                                   (__attribute__((address_space(3))) unsigned int*)l,
                                   16, 0, 0);
}

// ---------------- transpose + fp32->bf16: in (R x C) fp32 -> out (C x R) bf16 ----------------
__global__ __launch_bounds__(256) void transpose_k(const float* __restrict__ in,
                                                   unsigned short* __restrict__ out,
                                                   int R, int C){
  __shared__ unsigned short tile[32][33];
  int tx = threadIdx.x & 31, ty = threadIdx.x >> 5;
  int r0 = blockIdx.y * 32, c0 = blockIdx.x * 32;
#pragma unroll
  for (int t = 0; t < 4; ++t)
    tile[ty + t*8][tx] = f2b(in[(size_t)(r0 + ty + t*8) * C + c0 + tx]);
  __syncthreads();
#pragma unroll
  for (int t = 0; t < 4; ++t)
    out[(size_t)(c0 + ty + t*8) * R + r0 + tx] = tile[tx][ty + t*8];
}

// ---------------- ss init ----------------
__global__ __launch_bounds__(256) void ss_init_k(const float* __restrict__ bssq,
                                                 const float* __restrict__ bssk,
                                                 float* __restrict__ ss_q,
                                                 float* __restrict__ ss_kv){
  int idx = blockIdx.x*256 + threadIdx.x;          // 0..32767
  int which = idx >> 14, rem = idx & 16383;
  int j = rem & 2047;
  if (which) ss_kv[rem] = bssk[j];
  else       ss_q[rem]  = bssq[j];
}

// ---------------- ss main ----------------
__global__ __launch_bounds__(256) void ss2_k(const float* __restrict__ tvec,
                                             const float* __restrict__ Wssq,
                                             const float* __restrict__ Wssk,
                                             float* __restrict__ ss_q,
                                             float* __restrict__ ss_kv){
  const int which = blockIdx.z;
  const float* W = which ? Wssk : Wssq;
  float* ss = which ? ss_kv : ss_q;
  const int col = blockIdx.x*256 + threadIdx.x;
  const int k0 = blockIdx.y*64;

  __shared__ float sl[8][64];
  int idx = threadIdx.x;
#pragma unroll
  for (int t = 0; t < 2; ++t){
    int i = idx + t*256;
    int b = i >> 6, k = i & 63;
    float c = tvec[b*1024 + k0 + k];
    sl[b][k] = c / (1.f + __expf(-c));
  }
  __syncthreads();

  float acc[8] = {0.f,0.f,0.f,0.f,0.f,0.f,0.f,0.f};
#pragma unroll 8
  for (int k = 0; k < 64; ++k){
    float w = W[(size_t)(k0 + k)*2048 + col];
#pragma unroll
    for (int b = 0; b < 8; ++b) acc[b] += sl[b][k] * w;
  }
#pragma unroll
  for (int b = 0; b < 8; ++b)
    atomicAdd(&ss[b*2048 + col], acc[b]);
}

// ---------------- adaptive layernorm ----------------
__global__ __launch_bounds__(256) void ada_ln_k(const float* __restrict__ x,
                                                const float* __restrict__ ss,
                                                unsigned short* __restrict__ out,
                                                int L){
  int row = blockIdx.x;
  int b = row / L;
  const float* xr = x + (size_t)row * 1024;
  int tid = threadIdx.x;
  float4 v = *(const float4*)&xr[tid*4];
  float s = v.x + v.y + v.z + v.w;
  __shared__ float red[4];
#pragma unroll
  for (int o = 32; o > 0; o >>= 1) s += __shfl_xor(s, o, 64);
  if ((tid & 63) == 0) red[tid >> 6] = s;
  __syncthreads();
  float mu = (red[0]+red[1]+red[2]+red[3]) * (1.f/1024.f);
  __syncthreads();
  float vs = (v.x-mu)*(v.x-mu) + (v.y-mu)*(v.y-mu) + (v.z-mu)*(v.z-mu) + (v.w-mu)*(v.w-mu);
#pragma unroll
  for (int o = 32; o > 0; o >>= 1) vs += __shfl_xor(vs, o, 64);
  if ((tid & 63) == 0) red[tid >> 6] = vs;
  __syncthreads();
  float var = (red[0]+red[1]+red[2]+red[3]) * (1.f/1024.f);
  float inv = rsqrtf(var + 1e-5f);
  const float* sb = ss + (size_t)b*2048;
  float4 sc = *(const float4*)&sb[tid*4];
  float4 bi = *(const float4*)&sb[1024 + tid*4];
  u16x4 o4;
  o4[0] = f2b((1.f + sc.x) * ((v.x-mu)*inv) + bi.x);
  o4[1] = f2b((1.f + sc.y) * ((v.y-mu)*inv) + bi.y);
  o4[2] = f2b((1.f + sc.z) * ((v.z-mu)*inv) + bi.z);
  o4[3] = f2b((1.f + sc.w) * ((v.w-mu)*inv) + bi.w);
  *(u16x4*)&out[(size_t)row*1024 + tid*4] = o4;
}

// ---------------- GEMM 128x128, counted-vmcnt dbuf pipeline (KV projection) ----------------
__global__ __launch_bounds__(256) void gemm_bt_k(const unsigned short* __restrict__ A,
                                                 const unsigned short* __restrict__ BT,
                                                 const float* __restrict__ bias,
                                                 const float* __restrict__ resf,
                                                 unsigned short* __restrict__ Cb,
                                                 float* __restrict__ Cf,
                                                 _Float16* __restrict__ vT,
                                                 int M, int N, int K, int mode){
  __shared__ __attribute__((aligned(16))) unsigned short As[2][128*64];
  __shared__ __attribute__((aligned(16))) unsigned short Bs[2][128*64];
  const int tid = threadIdx.x;
  const int wave = tid >> 6, lane = tid & 63;
  const int lm = lane & 15, quad = lane >> 4;

  const int gx = gridDim.x;
  const int nwg = gx * gridDim.y;            // %8==0
  const int lid = blockIdx.y * gx + blockIdx.x;
  const int chunk = nwg >> 3;
  const int tile = (lid & 7) * chunk + (lid >> 3);
  const int m0 = (tile / gx) * 128, n0 = (tile % gx) * 128;

  const int wm = (wave >> 1) * 64, wn = (wave & 1) * 64;
  f32x4 acc[4][4];
#pragma unroll
  for (int i = 0; i < 4; ++i)
#pragma unroll
    for (int j = 0; j < 4; ++j) acc[i][j] = (f32x4){0.f,0.f,0.f,0.f};

  int rowc[4], colc[4];
#pragma unroll
  for (int r = 0; r < 4; ++r){
    int c = r*256 + tid;
    rowc[r] = c >> 3; colc[r] = (c & 7) * 8;
  }

#define STAGE128(buf, kk)                                                              \
  {                                                                                    \
    _Pragma("unroll")                                                                  \
    for (int r = 0; r < 4; ++r)                                                        \
      gld_lds16(&A[(size_t)(m0 + rowc[r])*K + (kk) + colc[r]], &As[buf][(r*256 + tid)*8]); \
    _Pragma("unroll")                                                                  \
    for (int r = 0; r < 4; ++r)                                                        \
      gld_lds16(&BT[(size_t)(n0 + rowc[r])*K + (kk) + colc[r]], &Bs[buf][(r*256 + tid)*8]); \
  }

  const int NT = K >> 6;
  STAGE128(0, 0);
  STAGE128(1, 64);
  asm volatile("s_waitcnt vmcnt(8)" ::: "memory");
  __builtin_amdgcn_s_barrier();

  for (int t = 0; t < NT; ++t){
    const int cur = t & 1;
#pragma unroll
    for (int ks = 0; ks < 2; ++ks){
      bf16x8 af[4], bfr[4];
#pragma unroll
      for (int i = 0; i < 4; ++i)
        af[i] = *(bf16x8*)&As[cur][(wm + i*16 + lm)*64 + ks*32 + quad*8];
#pragma unroll
      for (int j = 0; j < 4; ++j)
        bfr[j] = *(bf16x8*)&Bs[cur][(wn + j*16 + lm)*64 + ks*32 + quad*8];
#pragma unroll
      for (int i = 0; i < 4; ++i)
#pragma unroll
        for (int j = 0; j < 4; ++j)
          acc[i][j] = __builtin_amdgcn_mfma_f32_16x16x32_bf16(af[i], bfr[j], acc[i][j], 0, 0, 0);
    }
    if (t + 1 < NT){
      __builtin_amdgcn_s_barrier();
      if (t + 2 < NT){
        STAGE128(cur, (t + 2) << 6);
        asm volatile("s_waitcnt vmcnt(8)" ::: "memory");
      } else {
        asm volatile("s_waitcnt vmcnt(0)" ::: "memory");
      }
      __builtin_amdgcn_s_barrier();
    }
  }
#undef STAGE128

  if (mode == 2 && n0 >= 1024){
#pragma unroll
    for (int j = 0; j < 4; ++j){
      int col = n0 + wn + j*16 + lm;
      int d = col - 1024;
      float bv = bias[col];
#pragma unroll
      for (int i = 0; i < 4; ++i){
        int rowb = m0 + wm + i*16 + quad*4;
        int brow = rowb >> 9, l = rowb & 511;
        f16x4 h4;
#pragma unroll
        for (int p = 0; p < 4; ++p) h4[p] = (_Float16)(acc[i][j][p] + bv);
        *(f16x4*)&vT[((size_t)brow*1024 + d)*512 + l] = h4;
      }
    }
    return;
  }

#pragma unroll
  for (int j = 0; j < 4; ++j){
    int col = n0 + wn + j*16 + lm;
    float bv = bias[col];
#pragma unroll
    for (int i = 0; i < 4; ++i){
#pragma unroll
      for (int p = 0; p < 4; ++p){
        int row = m0 + wm + i*16 + quad*4 + p;
        float v = acc[i][j][p] + bv;
        if (mode == 1){
          Cf[(size_t)row*N + col] = v + resf[(size_t)row*N + col];
        } else {
          Cb[(size_t)row*1024 + col] = f2b(v);
        }
      }
    }
  }
}

// ---------------- GEMM 256x256, 8-phase K-half pipeline (T1+T2+T3+T4+T5) ----------------
// LDS [buf][ks][256 rows][32 cols] per operand: region = one K-half of one tile.
// Phases per 2 K-tiles (even tile->buf0, odd->buf1), ks-major order so Kh0 dies after
// phase 2 -> every half-stage has 6 phases (~2k cy) of flight. vmcnt(8) at even-phase
// ends retires exactly the 4 loads the phase-after-next reads.
// Swizzle (both sides): write src col = (c ^ ((row>>1)&3))*8; read chunk = quad ^ ((lm>>1)&3).
__global__ __launch_bounds__(512) void gemm256_k(const unsigned short* __restrict__ A,
                                                 const unsigned short* __restrict__ BT,
                                                 const float* __restrict__ bias,
                                                 const float* __restrict__ resf,
                                                 unsigned short* __restrict__ Cb,
                                                 float* __restrict__ Cf,
                                                 int M, int N, int K, int mode){
  __shared__ __attribute__((aligned(16))) unsigned short As[2][2][8192];
  __shared__ __attribute__((aligned(16))) unsigned short Bs[2][2][8192];
  const int tid = threadIdx.x;               // 0..511
  const int wave = tid >> 6, lane = tid & 63;
  const int lm = lane & 15, quad = lane >> 4;

  // XCD swizzle (nwg % 8 == 0)
  const int gx = gridDim.x;
  const int nwg = gx * gridDim.y;
  const int lid = blockIdx.y * gx + blockIdx.x;
  const int chunkw = nwg >> 3;
  const int tileid = (lid & 7) * chunkw + (lid >> 3);
  const int m0 = (tileid / gx) * 256, n0 = (tileid % gx) * 256;

  const int wm = (wave >> 2) * 128, wn = (wave & 3) * 64;   // 2x4 wave grid

  f32x4 acc[8][4];
#pragma unroll
  for (int i = 0; i < 8; ++i)
#pragma unroll
    for (int j = 0; j < 4; ++j) acc[i][j] = (f32x4){0.f,0.f,0.f,0.f};

  // staging map: lc = r*512+tid in [0,1024): row=lc>>2, c=lc&3; swizzled src col
  int srow[2], scol0[2];
#pragma unroll
  for (int r = 0; r < 2; ++r){
    int lc = r*512 + tid;
    srow[r]  = lc >> 2;
    scol0[r] = ((lc & 3) ^ ((srow[r] >> 1) & 3)) << 3;
  }

#define STG_A(bufb, ksb, kt)                                                            \
  { _Pragma("unroll")                                                                   \
    for (int r = 0; r < 2; ++r)                                                         \
      gld_lds16(&A[(size_t)(m0 + srow[r])*K + (kt)*64 + (ksb)*32 + scol0[r]],           \
                &As[bufb][ksb][(r*512 + tid)*8]); }
#define STG_B(bufb, ksb, kt)                                                            \
  { _Pragma("unroll")                                                                   \
    for (int r = 0; r < 2; ++r)                                                         \
      gld_lds16(&BT[(size_t)(n0 + srow[r])*K + (kt)*64 + (ksb)*32 + scol0[r]],          \
                &Bs[bufb][ksb][(r*512 + tid)*8]); }

  const int rc = (quad ^ ((lm >> 1) & 3)) * 8;   // swizzled read chunk (elements)
  const int arow = (wm + lm)*32 + rc;            // + (mh*4+i)*512 (imm)
  const int brow = (wn + lm)*32 + rc;            // + j*512 (imm)

#define PHASE(bufb, mh, ksb, STAGES, VM)                                                \
  { bf16x8 af[4], bfr[4];                                                               \
    _Pragma("unroll")                                                                   \
    for (int i = 0; i < 4; ++i)                                                         \
      af[i] = *(const bf16x8*)&As[bufb][ksb][arow + ((mh)*4 + i)*512];                  \
    _Pragma("unroll")                                                                   \
    for (int j = 0; j < 4; ++j)                                                         \
      bfr[j] = *(const bf16x8*)&Bs[bufb][ksb][brow + j*512];                            \
    STAGES;                                                                             \
    __builtin_amdgcn_s_barrier();                                                       \
    __builtin_amdgcn_s_setprio(1);                                                      \
    _Pragma("unroll")                                                                   \
    for (int i = 0; i < 4; ++i)                                                         \
      _Pragma("unroll")                                                                 \
      for (int j = 0; j < 4; ++j)                                                       \
        acc[(mh)*4 + i][j] =                                                            \
          __builtin_amdgcn_mfma_f32_16x16x32_bf16(af[i], bfr[j], acc[(mh)*4 + i][j], 0, 0, 0); \
    __builtin_amdgcn_s_setprio(0);                                                      \
    VM;                                                                                 \
    __builtin_amdgcn_s_barrier(); }

  const int NT = K >> 6;     // 16
  const int NU = NT >> 1;    // 8  (requires K % 128 == 0)

  // prologue: t0.Kh0, t0.Kh1, t1.Kh0 (12 loads); first 4 must land
  STG_A(0, 0, 0); STG_B(0, 0, 0);
  STG_A(0, 1, 0); STG_B(0, 1, 0);
  STG_A(1, 0, 1); STG_B(1, 0, 1);
  asm volatile("s_waitcnt vmcnt(8)" ::: "memory");
  __builtin_amdgcn_s_barrier();

  for (int u = 0; u < NU; ++u){
    const int t1 = 2*u + 1, t2 = 2*u + 2, t3 = 2*u + 3;
    const bool nlast = (u + 1 < NU);
    // P1..P4: even tile (buf0); P5..P8: odd tile (buf1). ks-major within tile.
    PHASE(0, 0, 0, { STG_A(1, 1, t1); }, {});
    PHASE(0, 1, 0, { STG_B(1, 1, t1); },
          { asm volatile("s_waitcnt vmcnt(8)" ::: "memory"); });
    PHASE(0, 0, 1, { if (nlast) STG_A(0, 0, t2); }, {});
    PHASE(0, 1, 1, { if (nlast) STG_B(0, 0, t2); },
          { if (nlast) asm volatile("s_waitcnt vmcnt(8)" ::: "memory");
            else       asm volatile("s_waitcnt vmcnt(4)" ::: "memory"); });
    PHASE(1, 0, 0, { if (nlast) STG_A(0, 1, t2); }, {});
    PHASE(1, 1, 0, { if (nlast) STG_B(0, 1, t2); },
          { if (nlast) asm volatile("s_waitcnt vmcnt(8)" ::: "memory");
            else       asm volatile("s_waitcnt vmcnt(0)" ::: "memory"); });
    PHASE(1, 0, 1, { if (nlast) STG_A(1, 0, t3); }, {});
    PHASE(1, 1, 1, { if (nlast) STG_B(1, 0, t3); },
          { if (nlast) asm volatile("s_waitcnt vmcnt(8)" ::: "memory"); });
  }
#undef PHASE
#undef STG_A
#undef STG_B

#pragma unroll
  for (int j = 0; j < 4; ++j){
    int col = n0 + wn + j*16 + lm;
    float bv = bias[col];
#pragma unroll
    for (int i = 0; i < 8; ++i){
#pragma unroll
      for (int p = 0; p < 4; ++p){
        int row = m0 + wm + i*16 + quad*4 + p;
        float v = acc[i][j][p] + bv;
        if (mode == 1){
          Cf[(size_t)row*N + col] = v + resf[(size_t)row*N + col];
        } else {
          Cb[(size_t)row*1024 + col] = f2b(v);
        }
      }
    }
  }
}

// ---------------- attention v5 ----------------
__global__ __launch_bounds__(256) void attn_k(const unsigned short* __restrict__ q,
                                              const unsigned short* __restrict__ kbuf,
                                              const _Float16* __restrict__ vT,
                                              unsigned short* __restrict__ out){
  const int lid = (blockIdx.z * gridDim.y + blockIdx.y) * gridDim.x + blockIdx.x; // 0..2047
  const int tile = (lid & 7) * 256 + (lid >> 3);
  const int qb = tile & 15, h = (tile >> 4) & 15, b = tile >> 8;
  const int tid = threadIdx.x;
  const int wave = tid >> 6, lane = tid & 63;
  const int lm = lane & 15, quad = lane >> 4;
  const int q0 = qb * 128;

  __shared__ __attribute__((aligned(16))) unsigned short Ks[64*72];
  __shared__ __attribute__((aligned(16))) _Float16      Vs[64*72];

  bf16x8 qf[2][2];
#pragma unroll
  for (int u = 0; u < 2; ++u){
    const unsigned short* qrow = q + ((size_t)b*2048 + q0 + wave*32 + u*16 + lm)*1024 + h*64;
    qf[u][0] = *(const bf16x8*)&qrow[quad*8];
    qf[u][1] = *(const bf16x8*)&qrow[32 + quad*8];
  }

  const unsigned short* kb = kbuf + ((size_t)b*512)*1024 + h*64;
  const _Float16*       vb = vT + ((size_t)b*1024 + h*64)*512;

  f32x4 oacc[2][4];
#pragma unroll
  for (int u = 0; u < 2; ++u)
#pragma unroll
    for (int nt = 0; nt < 4; ++nt) oacc[u][nt] = (f32x4){0.f,0.f,0.f,0.f};
  float m_run[2] = {-1e30f, -1e30f}, l_run[2] = {0.f, 0.f};

  const int srow = tid >> 3, scol = (tid & 7) * 8;

  for (int kt = 0; kt < 8; ++kt){
    const int l0 = kt * 64;
    __syncthreads();
#pragma unroll
    for (int r = 0; r < 2; ++r){
      int row = r*32 + srow;
      *(bf16x8*)&Ks[row*72 + scol] = *(const bf16x8*)&kb[(size_t)(l0 + row)*1024 + scol];
      *(f16x8*)&Vs[row*72 + scol]  = *(const f16x8*)&vb[(size_t)row*512 + l0 + scol];
    }
    __syncthreads();

    f32x4 sacc[2][4];
#pragma unroll
    for (int u = 0; u < 2; ++u)
#pragma unroll
      for (int s = 0; s < 4; ++s) sacc[u][s] = (f32x4){0.f,0.f,0.f,0.f};
#pragma unroll
    for (int s = 0; s < 4; ++s){
      bf16x8 kf0 = *(bf16x8*)&Ks[(s*16 + lm)*72 + quad*8];
      bf16x8 kf1 = *(bf16x8*)&Ks[(s*16 + lm)*72 + 32 + quad*8];
#pragma unroll
      for (int u = 0; u < 2; ++u){
        sacc[u][s] = __builtin_amdgcn_mfma_f32_16x16x32_bf16(kf0, qf[u][0], sacc[u][s], 0, 0, 0);
        sacc[u][s] = __builtin_amdgcn_mfma_f32_16x16x32_bf16(kf1, qf[u][1], sacc[u][s], 0, 0, 0);
      }
    }

    f16x4 pf[2][4];
#pragma unroll
    for (int u = 0; u < 2; ++u){
      float tm = -1e30f;
#pragma unroll
      for (int s = 0; s < 4; ++s)
#pragma unroll
        for (int p = 0; p < 4; ++p) tm = fmaxf(tm, sacc[u][s][p]);
      tm = fmaxf(tm, __shfl_xor(tm, 16, 64));
      tm = fmaxf(tm, __shfl_xor(tm, 32, 64));
      float m_new = fmaxf(m_run[u], tm * 0.125f);
      float alpha = __expf(m_run[u] - m_new);
      m_run[u] = m_new;
      l_run[u] *= alpha;
      float ap[4];
#pragma unroll
      for (int p = 0; p < 4; ++p) ap[p] = __shfl(alpha, quad*4 + p, 64);
#pragma unroll
      for (int nt = 0; nt < 4; ++nt){
        oacc[u][nt][0] *= ap[0]; oacc[u][nt][1] *= ap[1];
        oacc[u][nt][2] *= ap[2]; oacc[u][nt][3] *= ap[3];
      }
#pragma unroll
      for (int s = 0; s < 4; ++s)
#pragma unroll
        for (int p = 0; p < 4; ++p){
          float e = __expf(sacc[u][s][p] * 0.125f - m_new);
          l_run[u] += e;
          pf[u][s][p] = (_Float16)e;
        }
    }

#pragma unroll
    for (int s = 0; s < 4; ++s){
#pragma unroll
      for (int nt = 0; nt < 4; ++nt){
        f16x4 vf = *(const f16x4*)&Vs[(size_t)(nt*16 + lm)*72 + s*16 + quad*4];
#pragma unroll
        for (int u = 0; u < 2; ++u)
          oacc[u][nt] = __builtin_amdgcn_mfma_f32_16x16x16f16(pf[u][s], vf, oacc[u][nt], 0, 0, 0);
      }
    }
  }

#pragma unroll
  for (int u = 0; u < 2; ++u){
    float lr = l_run[u];
    lr += __shfl_xor(lr, 16, 64);
    lr += __shfl_xor(lr, 32, 64);
    float rinv = 1.f / lr;
    float rp[4];
#pragma unroll
    for (int p = 0; p < 4; ++p) rp[p] = __shfl(rinv, quad*4 + p, 64);
    const size_t obase = ((size_t)b*2048 + q0 + wave*32 + u*16) * 1024 + h*64;
#pragma unroll
    for (int nt = 0; nt < 4; ++nt)
#pragma unroll
      for (int p = 0; p < 4; ++p){
        int row = quad*4 + p;
        out[obase + (size_t)row*1024 + nt*16 + lm] = f2b(oacc[u][nt][p] * rp[p]);
      }
  }
}

extern "C" void kernel_launch(void* const* d_in, const int* in_sizes, int n_in,
                              void* d_out, int out_size, void* d_ws, size_t ws_size,
                              hipStream_t stream){
  const float* x_q  = (const float*)d_in[0];
  const float* x_kv = (const float*)d_in[1];
  const float* tvec = (const float*)d_in[2];
  const float* Wq   = (const float*)d_in[3];
  const float* bq   = (const float*)d_in[4];
  const float* Wkv  = (const float*)d_in[5];
  const float* bkv  = (const float*)d_in[6];
  const float* Wp   = (const float*)d_in[7];
  const float* bp   = (const float*)d_in[8];
  const float* Wssq = (const float*)d_in[9];
  const float* bssq = (const float*)d_in[10];
  const float* Wssk = (const float*)d_in[11];
  const float* bssk = (const float*)d_in[12];

  char* ws = (char*)d_ws;
  float*          ss_q  = (float*)(ws + 0);                    // 64 KB
  float*          ss_kv = (float*)(ws + 65536);                // 64 KB
  unsigned short* xq    = (unsigned short*)(ws + 131072);      // 32 MB bf16; reused as attn out
  unsigned short* xkv   = (unsigned short*)(ws + 33685504);    // 8 MB bf16
  unsigned short* qbuf  = (unsigned short*)(ws + 42074112);    // 32 MB bf16
  unsigned short* kbuf  = (unsigned short*)(ws + 75628544);    // 8 MB bf16
  _Float16*       vTbuf = (_Float16*)     (ws + 84017152);     // 8 MB f16
  unsigned short* WqT   = (unsigned short*)(ws + 92405760);    // 2 MB bf16
  unsigned short* WkvT  = (unsigned short*)(ws + 94502912);    // 4 MB bf16
  unsigned short* WpT   = (unsigned short*)(ws + 98697216);    // 2 MB bf16

  dim3 blk(256);
  transpose_k<<<dim3(32, 32), blk, 0, stream>>>(Wq,  WqT,  1024, 1024);
  transpose_k<<<dim3(64, 32), blk, 0, stream>>>(Wkv, WkvT, 1024, 2048);
  transpose_k<<<dim3(32, 32), blk, 0, stream>>>(Wp,  WpT,  1024, 1024);

  ss_init_k<<<dim3(128), blk, 0, stream>>>(bssq, bssk, ss_q, ss_kv);
  ss2_k<<<dim3(8, 16, 2), blk, 0, stream>>>(tvec, Wssq, Wssk, ss_q, ss_kv);

  ada_ln_k<<<dim3(16384), blk, 0, stream>>>(x_q,  ss_q,  xq,  2048);
  ada_ln_k<<<dim3(4096),  blk, 0, stream>>>(x_kv, ss_kv, xkv, 512);

  gemm256_k<<<dim3(4, 64), dim3(512), 0, stream>>>(xq, WqT, bq, nullptr, qbuf, nullptr,
                                                   16384, 1024, 1024, 0);
  gemm_bt_k<<<dim3(16, 32), blk, 0, stream>>>(xkv, WkvT, bkv, nullptr, kbuf, nullptr, vTbuf,
                                              4096, 2048, 1024, 2);

  attn_k<<<dim3(16, 16, 8), blk, 0, stream>>>(qbuf, kbuf, vTbuf, xq);

  gemm256_k<<<dim3(4, 64), dim3(512), 0, stream>>>(xq, WpT, bp, x_q, nullptr, (float*)d_out,
                                                   16384, 1024, 1024, 1);
}

// Round 10
// 414.838 us; speedup vs baseline: 1.0633x; 1.0009x over previous
//
#include <hip/hip_runtime.h>
#include <hip/hip_bf16.h>
#include <stdint.h>

typedef __attribute__((ext_vector_type(8))) short bf16x8;
typedef __attribute__((ext_vector_type(4))) float f32x4;
typedef __attribute__((ext_vector_type(4))) _Float16 f16x4;
typedef __attribute__((ext_vector_type(8))) _Float16 f16x8;
typedef __attribute__((ext_vector_type(4))) unsigned short u16x4;

__device__ __forceinline__ float b2f(unsigned short u){
  union { unsigned int i; float f; } x; x.i = ((unsigned int)u) << 16; return x.f;
}
__device__ __forceinline__ unsigned short f2b(float f){
  union { float f; unsigned int i; } x; x.f = f;
  unsigned int r = x.i + 0x7fffu + ((x.i >> 16) & 1u);
  return (unsigned short)(r >> 16);
}

__device__ __forceinline__ void gld_lds16(const void* g, void* l){
  __builtin_amdgcn_global_load_lds((const __attribute__((address_space(1))) unsigned int*)g,
                                   (__attribute__((address_space(3))) unsigned int*)l,
                                   16, 0, 0);
}

// ---------------- transpose + fp32->bf16: in (R x C) fp32 -> out (C x R) bf16 ----------------
__global__ __launch_bounds__(256) void transpose_k(const float* __restrict__ in,
                                                   unsigned short* __restrict__ out,
                                                   int R, int C){
  __shared__ unsigned short tile[32][33];
  int tx = threadIdx.x & 31, ty = threadIdx.x >> 5;
  int r0 = blockIdx.y * 32, c0 = blockIdx.x * 32;
#pragma unroll
  for (int t = 0; t < 4; ++t)
    tile[ty + t*8][tx] = f2b(in[(size_t)(r0 + ty + t*8) * C + c0 + tx]);
  __syncthreads();
#pragma unroll
  for (int t = 0; t < 4; ++t)
    out[(size_t)(c0 + ty + t*8) * R + r0 + tx] = tile[tx][ty + t*8];
}

// ---------------- ss init ----------------
__global__ __launch_bounds__(256) void ss_init_k(const float* __restrict__ bssq,
                                                 const float* __restrict__ bssk,
                                                 float* __restrict__ ss_q,
                                                 float* __restrict__ ss_kv){
  int idx = blockIdx.x*256 + threadIdx.x;          // 0..32767
  int which = idx >> 14, rem = idx & 16383;
  int j = rem & 2047;
  if (which) ss_kv[rem] = bssk[j];
  else       ss_q[rem]  = bssq[j];
}

// ---------------- ss main ----------------
__global__ __launch_bounds__(256) void ss2_k(const float* __restrict__ tvec,
                                             const float* __restrict__ Wssq,
                                             const float* __restrict__ Wssk,
                                             float* __restrict__ ss_q,
                                             float* __restrict__ ss_kv){
  const int which = blockIdx.z;
  const float* W = which ? Wssk : Wssq;
  float* ss = which ? ss_kv : ss_q;
  const int col = blockIdx.x*256 + threadIdx.x;
  const int k0 = blockIdx.y*64;

  __shared__ float sl[8][64];
  int idx = threadIdx.x;
#pragma unroll
  for (int t = 0; t < 2; ++t){
    int i = idx + t*256;
    int b = i >> 6, k = i & 63;
    float c = tvec[b*1024 + k0 + k];
    sl[b][k] = c / (1.f + __expf(-c));
  }
  __syncthreads();

  float acc[8] = {0.f,0.f,0.f,0.f,0.f,0.f,0.f,0.f};
#pragma unroll 8
  for (int k = 0; k < 64; ++k){
    float w = W[(size_t)(k0 + k)*2048 + col];
#pragma unroll
    for (int b = 0; b < 8; ++b) acc[b] += sl[b][k] * w;
  }
#pragma unroll
  for (int b = 0; b < 8; ++b)
    atomicAdd(&ss[b*2048 + col], acc[b]);
}

// ---------------- adaptive layernorm ----------------
__global__ __launch_bounds__(256) void ada_ln_k(const float* __restrict__ x,
                                                const float* __restrict__ ss,
                                                unsigned short* __restrict__ out,
                                                int L){
  int row = blockIdx.x;
  int b = row / L;
  const float* xr = x + (size_t)row * 1024;
  int tid = threadIdx.x;
  float4 v = *(const float4*)&xr[tid*4];
  float s = v.x + v.y + v.z + v.w;
  __shared__ float red[4];
#pragma unroll
  for (int o = 32; o > 0; o >>= 1) s += __shfl_xor(s, o, 64);
  if ((tid & 63) == 0) red[tid >> 6] = s;
  __syncthreads();
  float mu = (red[0]+red[1]+red[2]+red[3]) * (1.f/1024.f);
  __syncthreads();
  float vs = (v.x-mu)*(v.x-mu) + (v.y-mu)*(v.y-mu) + (v.z-mu)*(v.z-mu) + (v.w-mu)*(v.w-mu);
#pragma unroll
  for (int o = 32; o > 0; o >>= 1) vs += __shfl_xor(vs, o, 64);
  if ((tid & 63) == 0) red[tid >> 6] = vs;
  __syncthreads();
  float var = (red[0]+red[1]+red[2]+red[3]) * (1.f/1024.f);
  float inv = rsqrtf(var + 1e-5f);
  const float* sb = ss + (size_t)b*2048;
  float4 sc = *(const float4*)&sb[tid*4];
  float4 bi = *(const float4*)&sb[1024 + tid*4];
  u16x4 o4;
  o4[0] = f2b((1.f + sc.x) * ((v.x-mu)*inv) + bi.x);
  o4[1] = f2b((1.f + sc.y) * ((v.y-mu)*inv) + bi.y);
  o4[2] = f2b((1.f + sc.z) * ((v.z-mu)*inv) + bi.z);
  o4[3] = f2b((1.f + sc.w) * ((v.w-mu)*inv) + bi.w);
  *(u16x4*)&out[(size_t)row*1024 + tid*4] = o4;
}

// ---------------- GEMM 128x128, counted-vmcnt dbuf pipeline (KV projection) ----------------
__global__ __launch_bounds__(256) void gemm_bt_k(const unsigned short* __restrict__ A,
                                                 const unsigned short* __restrict__ BT,
                                                 const float* __restrict__ bias,
                                                 const float* __restrict__ resf,
                                                 unsigned short* __restrict__ Cb,
                                                 float* __restrict__ Cf,
                                                 _Float16* __restrict__ vT,
                                                 int M, int N, int K, int mode){
  __shared__ __attribute__((aligned(16))) unsigned short As[2][128*64];
  __shared__ __attribute__((aligned(16))) unsigned short Bs[2][128*64];
  const int tid = threadIdx.x;
  const int wave = tid >> 6, lane = tid & 63;
  const int lm = lane & 15, quad = lane >> 4;

  const int gx = gridDim.x;
  const int nwg = gx * gridDim.y;            // %8==0
  const int lid = blockIdx.y * gx + blockIdx.x;
  const int chunk = nwg >> 3;
  const int tile = (lid & 7) * chunk + (lid >> 3);
  const int m0 = (tile / gx) * 128, n0 = (tile % gx) * 128;

  const int wm = (wave >> 1) * 64, wn = (wave & 1) * 64;
  f32x4 acc[4][4];
#pragma unroll
  for (int i = 0; i < 4; ++i)
#pragma unroll
    for (int j = 0; j < 4; ++j) acc[i][j] = (f32x4){0.f,0.f,0.f,0.f};

  int rowc[4], colc[4];
#pragma unroll
  for (int r = 0; r < 4; ++r){
    int c = r*256 + tid;
    rowc[r] = c >> 3; colc[r] = (c & 7) * 8;
  }

#define STAGE128(buf, kk)                                                              \
  {                                                                                    \
    _Pragma("unroll")                                                                  \
    for (int r = 0; r < 4; ++r)                                                        \
      gld_lds16(&A[(size_t)(m0 + rowc[r])*K + (kk) + colc[r]], &As[buf][(r*256 + tid)*8]); \
    _Pragma("unroll")                                                                  \
    for (int r = 0; r < 4; ++r)                                                        \
      gld_lds16(&BT[(size_t)(n0 + rowc[r])*K + (kk) + colc[r]], &Bs[buf][(r*256 + tid)*8]); \
  }

  const int NT = K >> 6;
  STAGE128(0, 0);
  STAGE128(1, 64);
  asm volatile("s_waitcnt vmcnt(8)" ::: "memory");
  __builtin_amdgcn_s_barrier();

  for (int t = 0; t < NT; ++t){
    const int cur = t & 1;
#pragma unroll
    for (int ks = 0; ks < 2; ++ks){
      bf16x8 af[4], bfr[4];
#pragma unroll
      for (int i = 0; i < 4; ++i)
        af[i] = *(bf16x8*)&As[cur][(wm + i*16 + lm)*64 + ks*32 + quad*8];
#pragma unroll
      for (int j = 0; j < 4; ++j)
        bfr[j] = *(bf16x8*)&Bs[cur][(wn + j*16 + lm)*64 + ks*32 + quad*8];
#pragma unroll
      for (int i = 0; i < 4; ++i)
#pragma unroll
        for (int j = 0; j < 4; ++j)
          acc[i][j] = __builtin_amdgcn_mfma_f32_16x16x32_bf16(af[i], bfr[j], acc[i][j], 0, 0, 0);
    }
    if (t + 1 < NT){
      __builtin_amdgcn_s_barrier();
      if (t + 2 < NT){
        STAGE128(cur, (t + 2) << 6);
        asm volatile("s_waitcnt vmcnt(8)" ::: "memory");
      } else {
        asm volatile("s_waitcnt vmcnt(0)" ::: "memory");
      }
      __builtin_amdgcn_s_barrier();
    }
  }
#undef STAGE128

  if (mode == 2 && n0 >= 1024){
#pragma unroll
    for (int j = 0; j < 4; ++j){
      int col = n0 + wn + j*16 + lm;
      int d = col - 1024;
      float bv = bias[col];
#pragma unroll
      for (int i = 0; i < 4; ++i){
        int rowb = m0 + wm + i*16 + quad*4;
        int brow = rowb >> 9, l = rowb & 511;
        f16x4 h4;
#pragma unroll
        for (int p = 0; p < 4; ++p) h4[p] = (_Float16)(acc[i][j][p] + bv);
        *(f16x4*)&vT[((size_t)brow*1024 + d)*512 + l] = h4;
      }
    }
    return;
  }

#pragma unroll
  for (int j = 0; j < 4; ++j){
    int col = n0 + wn + j*16 + lm;
    float bv = bias[col];
#pragma unroll
    for (int i = 0; i < 4; ++i){
#pragma unroll
      for (int p = 0; p < 4; ++p){
        int row = m0 + wm + i*16 + quad*4 + p;
        float v = acc[i][j][p] + bv;
        if (mode == 1){
          Cf[(size_t)row*N + col] = v + resf[(size_t)row*N + col];
        } else {
          Cb[(size_t)row*1024 + col] = f2b(v);
        }
      }
    }
  }
}

// ---------------- GEMM 256x256, 8-phase K-half pipeline (T1+T2+T3+T4+T5) ----------------
__global__ __launch_bounds__(512) void gemm256_k(const unsigned short* __restrict__ A,
                                                 const unsigned short* __restrict__ BT,
                                                 const float* __restrict__ bias,
                                                 const float* __restrict__ resf,
                                                 unsigned short* __restrict__ Cb,
                                                 float* __restrict__ Cf,
                                                 int M, int N, int K, int mode){
  __shared__ __attribute__((aligned(16))) unsigned short As[2][2][8192];
  __shared__ __attribute__((aligned(16))) unsigned short Bs[2][2][8192];
  const int tid = threadIdx.x;               // 0..511
  const int wave = tid >> 6, lane = tid & 63;
  const int lm = lane & 15, quad = lane >> 4;

  const int gx = gridDim.x;
  const int nwg = gx * gridDim.y;
  const int lid = blockIdx.y * gx + blockIdx.x;
  const int chunkw = nwg >> 3;
  const int tileid = (lid & 7) * chunkw + (lid >> 3);
  const int m0 = (tileid / gx) * 256, n0 = (tileid % gx) * 256;

  const int wm = (wave >> 2) * 128, wn = (wave & 3) * 64;   // 2x4 wave grid

  f32x4 acc[8][4];
#pragma unroll
  for (int i = 0; i < 8; ++i)
#pragma unroll
    for (int j = 0; j < 4; ++j) acc[i][j] = (f32x4){0.f,0.f,0.f,0.f};

  int srow[2], scol0[2];
#pragma unroll
  for (int r = 0; r < 2; ++r){
    int lc = r*512 + tid;
    srow[r]  = lc >> 2;
    scol0[r] = ((lc & 3) ^ ((srow[r] >> 1) & 3)) << 3;
  }

#define STG_A(bufb, ksb, kt)                                                            \
  { _Pragma("unroll")                                                                   \
    for (int r = 0; r < 2; ++r)                                                         \
      gld_lds16(&A[(size_t)(m0 + srow[r])*K + (kt)*64 + (ksb)*32 + scol0[r]],           \
                &As[bufb][ksb][(r*512 + tid)*8]); }
#define STG_B(bufb, ksb, kt)                                                            \
  { _Pragma("unroll")                                                                   \
    for (int r = 0; r < 2; ++r)                                                         \
      gld_lds16(&BT[(size_t)(n0 + srow[r])*K + (kt)*64 + (ksb)*32 + scol0[r]],          \
                &Bs[bufb][ksb][(r*512 + tid)*8]); }

  const int rc = (quad ^ ((lm >> 1) & 3)) * 8;   // swizzled read chunk (elements)
  const int arow = (wm + lm)*32 + rc;
  const int brow = (wn + lm)*32 + rc;

#define PHASE(bufb, mh, ksb, STAGES, VM)                                                \
  { bf16x8 af[4], bfr[4];                                                               \
    _Pragma("unroll")                                                                   \
    for (int i = 0; i < 4; ++i)                                                         \
      af[i] = *(const bf16x8*)&As[bufb][ksb][arow + ((mh)*4 + i)*512];                  \
    _Pragma("unroll")                                                                   \
    for (int j = 0; j < 4; ++j)                                                         \
      bfr[j] = *(const bf16x8*)&Bs[bufb][ksb][brow + j*512];                            \
    STAGES;                                                                             \
    __builtin_amdgcn_s_barrier();                                                       \
    __builtin_amdgcn_s_setprio(1);                                                      \
    _Pragma("unroll")                                                                   \
    for (int i = 0; i < 4; ++i)                                                         \
      _Pragma("unroll")                                                                 \
      for (int j = 0; j < 4; ++j)                                                       \
        acc[(mh)*4 + i][j] =                                                            \
          __builtin_amdgcn_mfma_f32_16x16x32_bf16(af[i], bfr[j], acc[(mh)*4 + i][j], 0, 0, 0); \
    __builtin_amdgcn_s_setprio(0);                                                      \
    VM;                                                                                 \
    __builtin_amdgcn_s_barrier(); }

  const int NT = K >> 6;     // 16
  const int NU = NT >> 1;    // 8

  STG_A(0, 0, 0); STG_B(0, 0, 0);
  STG_A(0, 1, 0); STG_B(0, 1, 0);
  STG_A(1, 0, 1); STG_B(1, 0, 1);
  asm volatile("s_waitcnt vmcnt(8)" ::: "memory");
  __builtin_amdgcn_s_barrier();

  for (int u = 0; u < NU; ++u){
    const int t1 = 2*u + 1, t2 = 2*u + 2, t3 = 2*u + 3;
    const bool nlast = (u + 1 < NU);
    PHASE(0, 0, 0, { STG_A(1, 1, t1); }, {});
    PHASE(0, 1, 0, { STG_B(1, 1, t1); },
          { asm volatile("s_waitcnt vmcnt(8)" ::: "memory"); });
    PHASE(0, 0, 1, { if (nlast) STG_A(0, 0, t2); }, {});
    PHASE(0, 1, 1, { if (nlast) STG_B(0, 0, t2); },
          { if (nlast) asm volatile("s_waitcnt vmcnt(8)" ::: "memory");
            else       asm volatile("s_waitcnt vmcnt(4)" ::: "memory"); });
    PHASE(1, 0, 0, { if (nlast) STG_A(0, 1, t2); }, {});
    PHASE(1, 1, 0, { if (nlast) STG_B(0, 1, t2); },
          { if (nlast) asm volatile("s_waitcnt vmcnt(8)" ::: "memory");
            else       asm volatile("s_waitcnt vmcnt(0)" ::: "memory"); });
    PHASE(1, 0, 1, { if (nlast) STG_A(1, 0, t3); }, {});
    PHASE(1, 1, 1, { if (nlast) STG_B(1, 0, t3); },
          { if (nlast) asm volatile("s_waitcnt vmcnt(8)" ::: "memory"); });
  }
#undef PHASE
#undef STG_A
#undef STG_B

#pragma unroll
  for (int j = 0; j < 4; ++j){
    int col = n0 + wn + j*16 + lm;
    float bv = bias[col];
#pragma unroll
    for (int i = 0; i < 8; ++i){
#pragma unroll
      for (int p = 0; p < 4; ++p){
        int row = m0 + wm + i*16 + quad*4 + p;
        float v = acc[i][j][p] + bv;
        if (mode == 1){
          Cf[(size_t)row*N + col] = v + resf[(size_t)row*N + col];
        } else {
          Cb[(size_t)row*1024 + col] = f2b(v);
        }
      }
    }
  }
}

// ---------------- attention v6: async-stage + LDS dbuf + pad76 + defer-max ----------------
// v5 counters: dur 81us, VALUBusy 55.7, MfmaUtil 26, LDS conflicts 6.3M (4-way at pad 72).
// Changes: (1) reg-staged K/V with next-tile loads issued before compute (T14);
// (2) Ks/Vs double-buffered, row pad 72 -> 76 shorts (stride 152B = 38 dw = 6 mod 32 -> 2-way);
// (3) defer-max: skip rescale (exp + 8 shfl + 32 mul) when tile max does not grow (T13, thr=0).
__global__ __launch_bounds__(256) void attn_k(const unsigned short* __restrict__ q,
                                              const unsigned short* __restrict__ kbuf,
                                              const _Float16* __restrict__ vT,
                                              unsigned short* __restrict__ out){
  const int lid = (blockIdx.z * gridDim.y + blockIdx.y) * gridDim.x + blockIdx.x; // 0..2047
  const int tile = (lid & 7) * 256 + (lid >> 3);
  const int qb = tile & 15, h = (tile >> 4) & 15, b = tile >> 8;
  const int tid = threadIdx.x;
  const int wave = tid >> 6, lane = tid & 63;
  const int lm = lane & 15, quad = lane >> 4;
  const int q0 = qb * 128;

  __shared__ __attribute__((aligned(16))) unsigned short Ks[2][64*76];
  __shared__ __attribute__((aligned(16))) _Float16      Vs[2][64*76];

  bf16x8 qf[2][2];
#pragma unroll
  for (int u = 0; u < 2; ++u){
    const unsigned short* qrow = q + ((size_t)b*2048 + q0 + wave*32 + u*16 + lm)*1024 + h*64;
    qf[u][0] = *(const bf16x8*)&qrow[quad*8];
    qf[u][1] = *(const bf16x8*)&qrow[32 + quad*8];
  }

  const unsigned short* kb = kbuf + ((size_t)b*512)*1024 + h*64;
  const _Float16*       vb = vT + ((size_t)b*1024 + h*64)*512;

  f32x4 oacc[2][4];
#pragma unroll
  for (int u = 0; u < 2; ++u)
#pragma unroll
    for (int nt = 0; nt < 4; ++nt) oacc[u][nt] = (f32x4){0.f,0.f,0.f,0.f};
  float m_run[2] = {-1e30f, -1e30f}, l_run[2] = {0.f, 0.f};

  const int srow = tid >> 3, scol = (tid & 7) * 8;

  // prologue: load tile 0 into registers
  bf16x8 kreg[2];
  f16x8  vreg[2];
#pragma unroll
  for (int r = 0; r < 2; ++r){
    int row = r*32 + srow;
    kreg[r] = *(const bf16x8*)&kb[(size_t)row*1024 + scol];
    vreg[r] = *(const f16x8*)&vb[(size_t)row*512 + scol];
  }

  for (int kt = 0; kt < 8; ++kt){
    const int buf = kt & 1;
    __syncthreads();                       // prior compute done reading buf
#pragma unroll
    for (int r = 0; r < 2; ++r){
      int row = r*32 + srow;
      *(bf16x8*)&Ks[buf][row*76 + scol] = kreg[r];
      *(f16x8*)&Vs[buf][row*76 + scol]  = vreg[r];
    }
    if (kt + 1 < 8){                       // issue next-tile loads; land under compute
      const int l1 = (kt + 1) * 64;
#pragma unroll
      for (int r = 0; r < 2; ++r){
        int row = r*32 + srow;
        kreg[r] = *(const bf16x8*)&kb[(size_t)(l1 + row)*1024 + scol];
        vreg[r] = *(const f16x8*)&vb[(size_t)row*512 + l1 + scol];
      }
    }
    __syncthreads();                       // LDS writes visible

    f32x4 sacc[2][4];
#pragma unroll
    for (int u = 0; u < 2; ++u)
#pragma unroll
      for (int s = 0; s < 4; ++s) sacc[u][s] = (f32x4){0.f,0.f,0.f,0.f};
#pragma unroll
    for (int s = 0; s < 4; ++s){
      bf16x8 kf0 = *(bf16x8*)&Ks[buf][(s*16 + lm)*76 + quad*8];
      bf16x8 kf1 = *(bf16x8*)&Ks[buf][(s*16 + lm)*76 + 32 + quad*8];
#pragma unroll
      for (int u = 0; u < 2; ++u){
        sacc[u][s] = __builtin_amdgcn_mfma_f32_16x16x32_bf16(kf0, qf[u][0], sacc[u][s], 0, 0, 0);
        sacc[u][s] = __builtin_amdgcn_mfma_f32_16x16x32_bf16(kf1, qf[u][1], sacc[u][s], 0, 0, 0);
      }
    }

    f16x4 pf[2][4];
#pragma unroll
    for (int u = 0; u < 2; ++u){
      float tm = -1e30f;
#pragma unroll
      for (int s = 0; s < 4; ++s)
#pragma unroll
        for (int p = 0; p < 4; ++p) tm = fmaxf(tm, sacc[u][s][p]);
      tm = fmaxf(tm, __shfl_xor(tm, 16, 64));
      tm = fmaxf(tm, __shfl_xor(tm, 32, 64));
      tm *= 0.125f;
      if (__any(tm > m_run[u])){           // defer-max: rescale only when max grows
        float m_new = fmaxf(m_run[u], tm);
        float alpha = __expf(m_run[u] - m_new);
        m_run[u] = m_new;
        l_run[u] *= alpha;
        float ap[4];
#pragma unroll
        for (int p = 0; p < 4; ++p) ap[p] = __shfl(alpha, quad*4 + p, 64);
#pragma unroll
        for (int nt = 0; nt < 4; ++nt){
          oacc[u][nt][0] *= ap[0]; oacc[u][nt][1] *= ap[1];
          oacc[u][nt][2] *= ap[2]; oacc[u][nt][3] *= ap[3];
        }
      }
#pragma unroll
      for (int s = 0; s < 4; ++s)
#pragma unroll
        for (int p = 0; p < 4; ++p){
          float e = __expf(sacc[u][s][p] * 0.125f - m_run[u]);
          l_run[u] += e;
          pf[u][s][p] = (_Float16)e;
        }
    }

#pragma unroll
    for (int s = 0; s < 4; ++s){
#pragma unroll
      for (int nt = 0; nt < 4; ++nt){
        f16x4 vf = *(const f16x4*)&Vs[buf][(size_t)(nt*16 + lm)*76 + s*16 + quad*4];
#pragma unroll
        for (int u = 0; u < 2; ++u)
          oacc[u][nt] = __builtin_amdgcn_mfma_f32_16x16x16f16(pf[u][s], vf, oacc[u][nt], 0, 0, 0);
      }
    }
  }

#pragma unroll
  for (int u = 0; u < 2; ++u){
    float lr = l_run[u];
    lr += __shfl_xor(lr, 16, 64);
    lr += __shfl_xor(lr, 32, 64);
    float rinv = 1.f / lr;
    float rp[4];
#pragma unroll
    for (int p = 0; p < 4; ++p) rp[p] = __shfl(rinv, quad*4 + p, 64);
    const size_t obase = ((size_t)b*2048 + q0 + wave*32 + u*16) * 1024 + h*64;
#pragma unroll
    for (int nt = 0; nt < 4; ++nt)
#pragma unroll
      for (int p = 0; p < 4; ++p){
        int row = quad*4 + p;
        out[obase + (size_t)row*1024 + nt*16 + lm] = f2b(oacc[u][nt][p] * rp[p]);
      }
  }
}

extern "C" void kernel_launch(void* const* d_in, const int* in_sizes, int n_in,
                              void* d_out, int out_size, void* d_ws, size_t ws_size,
                              hipStream_t stream){
  const float* x_q  = (const float*)d_in[0];
  const float* x_kv = (const float*)d_in[1];
  const float* tvec = (const float*)d_in[2];
  const float* Wq   = (const float*)d_in[3];
  const float* bq   = (const float*)d_in[4];
  const float* Wkv  = (const float*)d_in[5];
  const float* bkv  = (const float*)d_in[6];
  const float* Wp   = (const float*)d_in[7];
  const float* bp   = (const float*)d_in[8];
  const float* Wssq = (const float*)d_in[9];
  const float* bssq = (const float*)d_in[10];
  const float* Wssk = (const float*)d_in[11];
  const float* bssk = (const float*)d_in[12];

  char* ws = (char*)d_ws;
  float*          ss_q  = (float*)(ws + 0);                    // 64 KB
  float*          ss_kv = (float*)(ws + 65536);                // 64 KB
  unsigned short* xq    = (unsigned short*)(ws + 131072);      // 32 MB bf16; reused as attn out
  unsigned short* xkv   = (unsigned short*)(ws + 33685504);    // 8 MB bf16
  unsigned short* qbuf  = (unsigned short*)(ws + 42074112);    // 32 MB bf16
  unsigned short* kbuf  = (unsigned short*)(ws + 75628544);    // 8 MB bf16
  _Float16*       vTbuf = (_Float16*)     (ws + 84017152);     // 8 MB f16
  unsigned short* WqT   = (unsigned short*)(ws + 92405760);    // 2 MB bf16
  unsigned short* WkvT  = (unsigned short*)(ws + 94502912);    // 4 MB bf16
  unsigned short* WpT   = (unsigned short*)(ws + 98697216);    // 2 MB bf16

  dim3 blk(256);
  transpose_k<<<dim3(32, 32), blk, 0, stream>>>(Wq,  WqT,  1024, 1024);
  transpose_k<<<dim3(64, 32), blk, 0, stream>>>(Wkv, WkvT, 1024, 2048);
  transpose_k<<<dim3(32, 32), blk, 0, stream>>>(Wp,  WpT,  1024, 1024);

  ss_init_k<<<dim3(128), blk, 0, stream>>>(bssq, bssk, ss_q, ss_kv);
  ss2_k<<<dim3(8, 16, 2), blk, 0, stream>>>(tvec, Wssq, Wssk, ss_q, ss_kv);

  ada_ln_k<<<dim3(16384), blk, 0, stream>>>(x_q,  ss_q,  xq,  2048);
  ada_ln_k<<<dim3(4096),  blk, 0, stream>>>(x_kv, ss_kv, xkv, 512);

  gemm256_k<<<dim3(4, 64), dim3(512), 0, stream>>>(xq, WqT, bq, nullptr, qbuf, nullptr,
                                                   16384, 1024, 1024, 0);
  gemm_bt_k<<<dim3(16, 32), blk, 0, stream>>>(xkv, WkvT, bkv, nullptr, kbuf, nullptr, vTbuf,
                                              4096, 2048, 1024, 2);

  attn_k<<<dim3(16, 16, 8), blk, 0, stream>>>(qbuf, kbuf, vTbuf, xq);

  gemm256_k<<<dim3(4, 64), dim3(512), 0, stream>>>(xq, WpT, bp, x_q, nullptr, (float*)d_out,
                                                   16384, 1024, 1024, 1);
}